// Round 7
// baseline (1217.919 us; speedup 1.0000x reference)
//
#include <hip/hip_runtime.h>
#include <hip/hip_bf16.h>

#define DEV __device__ __forceinline__

namespace {

constexpr int Bn  = 4, SEQ = 1024, NV = 32, PL = 16, D = 512, H = 8, DFF = 2048;
constexpr int P   = SEQ / PL;    // 64 patches
constexpr int L   = P * NV;      // 2048 tokens per batch
constexpr int M   = Bn * L;      // 8192 total token rows
constexpr int WIN = 4;

using short8   = __attribute__((ext_vector_type(8))) short;
using ushort8  = __attribute__((ext_vector_type(8))) unsigned short;
using ushort4v = __attribute__((ext_vector_type(4))) unsigned short;
using float4v  = __attribute__((ext_vector_type(4))) float;

DEV float b2f(unsigned short u) { return __uint_as_float(((unsigned)u) << 16); }
DEV unsigned short f2b(float f) {
  unsigned fb = __float_as_uint(f);
  return (unsigned short)((fb + 0x7FFFu + ((fb >> 16) & 1u)) >> 16);
}
// flag-dispatched float load from an input tensor: bf=1 -> bf16, 0 -> fp32
DEV float ldf(const void* p, size_t idx, int bf) {
  if (bf) return b2f(((const unsigned short*)p)[idx]);
  return ((const float*)p)[idx];
}
// async global->LDS 16B: lds dest = wave-uniform base + lane*16
DEV void gll16(const void* gp, void* lp) {
  __builtin_amdgcn_global_load_lds(
      (const __attribute__((address_space(1))) void*)gp,
      (__attribute__((address_space(3))) void*)lp, 16, 0, 0);
}

// ---------------------------------------------------------------------------
// k_setup: detect float dtype + mask format, canonicalize mask, count masked.
// ---------------------------------------------------------------------------
__global__ void k_setup(const void* gf, const void* mask_raw, int* mask_i,
                        int* flags, float* scal) {
  __shared__ int s_gt1, s_oth, s_cnt;
  int tid = threadIdx.x;
  if (tid == 0) { s_gt1 = 0; s_oth = 0; s_cnt = 0; }
  __syncthreads();
  const unsigned* mw = (const unsigned*)mask_raw;
  int gt1 = 0, oth = 0;
  for (int i = tid; i < 2048; i += 256) {
    unsigned w = mw[i];
    if (w > 1u) { gt1 = 1; if (w != 0x3F800000u) oth = 1; }
  }
  if (gt1) atomicOr(&s_gt1, 1);
  if (oth) atomicOr(&s_oth, 1);
  __syncthreads();
  int fmt = (!s_gt1) ? 0 : (!s_oth ? 1 : 2);  // 0=int32, 1=f32, 2=bytes
  int cnt = 0;
  for (int i = tid; i < Bn * P * NV; i += 256) {
    int m;
    if (fmt == 0)      m = ((const int*)mask_raw)[i] != 0;
    else if (fmt == 1) m = ((const float*)mask_raw)[i] != 0.0f;
    else               m = ((const unsigned char*)mask_raw)[i] != 0;
    mask_i[i] = m; cnt += m;
  }
  atomicAdd(&s_cnt, cnt);
  __syncthreads();
  if (tid == 0) {
    unsigned w = *(const unsigned*)gf;
    flags[0] = ((w & 0xFFFFu) == 0x3F80u) ? 1 : 0;
    flags[1] = s_cnt;
    scal[0] = 0.f;
  }
}

// ---------------------------------------------------------------------------
// k_prep: blocks 0..31 -> per-(b,v) stats; blocks 32.. -> gather biases,
// final-LN weights (fp32), b_proj (fp32), and WpT (bf16 [t][d]).
// ---------------------------------------------------------------------------
__global__ void k_prep(const void* x, const void* bq, const void* bk,
                       const void* bv, const void* bo, const void* b1,
                       const void* b2, const void* gf, const void* bff,
                       const void* Wp, const void* bp, const int* flags,
                       float* means, float* stdev, float* biasf, float* lnw,
                       unsigned short* WpT) {
  int bf = flags[0];
  int tid = threadIdx.x;
  if (blockIdx.x < 32) {
    int bv_ = blockIdx.x * 4 + (tid >> 6);
    int b = bv_ >> 5, v = bv_ & 31;
    int lane = tid & 63;
    float s = 0.f, s2 = 0.f;
    for (int t = lane; t < SEQ; t += 64) {
      float val = ldf(x, (size_t)b * SEQ * NV + (size_t)t * NV + v, bf);
      s += val; s2 += val * val;
    }
    for (int off = 32; off; off >>= 1) {
      s += __shfl_xor(s, off); s2 += __shfl_xor(s2, off);
    }
    if (lane == 0) {
      float m = s / (float)SEQ;
      means[bv_] = m;
      stdev[bv_] = sqrtf(s2 / (float)SEQ - m * m + 1e-5f);
    }
    return;
  }
  int i = (blockIdx.x - 32) * 256 + tid;
  if (i < 18432) {
    int l = i / 4608, r = i % 4608;
    if (r < 1536) {
      float v = (r < 512) ? ldf(bq, l * 512 + r, bf)
              : (r < 1024) ? ldf(bk, l * 512 + r - 512, bf)
                           : ldf(bv, l * 512 + r - 1024, bf);
      biasf[l * 1536 + r] = v;
    } else if (r < 2048) {
      biasf[6144 + l * 512 + (r - 1536)] = ldf(bo, l * 512 + r - 1536, bf);
    } else if (r < 4096) {
      biasf[8192 + l * 2048 + (r - 2048)] = ldf(b1, l * 2048 + r - 2048, bf);
    } else {
      biasf[16384 + l * 512 + (r - 4096)] = ldf(b2, l * 512 + r - 4096, bf);
    }
  } else if (i < 19456) {
    int j = i - 18432;
    lnw[j] = (j < 512) ? ldf(gf, j, bf) : ldf(bff, j - 512, bf);
  } else if (i < 19472) {
    lnw[1024 + (i - 19456)] = ldf(bp, i - 19456, bf);
  } else if (i < 27664) {
    int j = i - 19472; int t = j >> 9, d = j & 511;
    WpT[j] = f2b(ldf(Wp, d * 16 + t, bf));
  }
}

// ---------------------------------------------------------------------------
// k_transpose_all: all 6 weight transposes in one dispatch.
// dst[l][n][k] (bf16) = src[l][k][n]. 32x32 LDS tile per block.
// ---------------------------------------------------------------------------
__global__ void k_transpose_all(const void* Wq, const void* Wk, const void* Wv,
                                const void* Wo, const void* W1, const void* W2,
                                unsigned short* qkvT, unsigned short* WoT,
                                unsigned short* W1T, unsigned short* W2T,
                                const int* flags) {
  int bf = flags[0];
  int id = blockIdx.x;
  const void* src; unsigned short* dst;
  int Kd, Nd, l, n0, k0, dstOff = 0;
  size_t srcLS, dstLS;
  if (id < 4096) {
    int tensor = id >> 10, rem = id & 1023;
    l = rem >> 8; int t = rem & 255;
    n0 = (t & 15) * 32; k0 = (t >> 4) * 32;
    Kd = 512; Nd = 512; srcLS = 262144;
    if (tensor == 0)      { src = Wq; dst = qkvT; dstLS = 786432; dstOff = 0; }
    else if (tensor == 1) { src = Wk; dst = qkvT; dstLS = 786432; dstOff = 262144; }
    else if (tensor == 2) { src = Wv; dst = qkvT; dstLS = 786432; dstOff = 524288; }
    else                  { src = Wo; dst = WoT;  dstLS = 262144; }
  } else if (id < 8192) {
    int rem = id - 4096; l = rem >> 10; int t = rem & 1023;
    n0 = (t & 63) * 32; k0 = (t >> 6) * 32;
    Kd = 512; Nd = 2048; srcLS = 1048576; src = W1; dst = W1T; dstLS = 1048576;
  } else {
    int rem = id - 8192; l = rem >> 10; int t = rem & 1023;
    n0 = (t & 15) * 32; k0 = (t >> 4) * 32;
    Kd = 2048; Nd = 512; srcLS = 1048576; src = W2; dst = W2T; dstLS = 1048576;
  }
  int tx = threadIdx.x & 31, ty = threadIdx.x >> 5;
  __shared__ float tile[32][33];
  for (int rr = ty; rr < 32; rr += 8)
    tile[rr][tx] =
        ldf(src, (size_t)l * srcLS + (size_t)(k0 + rr) * Nd + n0 + tx, bf);
  __syncthreads();
  for (int rr = ty; rr < 32; rr += 8)
    dst[(size_t)l * dstLS + dstOff + (size_t)(n0 + rr) * Kd + k0 + tx] =
        f2b(tile[tx][rr]);
}

// ---------------------------------------------------------------------------
// k_embed: patchify + instance-normalize, write patches (fp32) and embedded
// tokens (bf16), zeroing masked tokens. One block (128 thr) per token.
// ---------------------------------------------------------------------------
__global__ void k_embed(const void* x, const void* We, const void* be,
                        const int* flags, const int* mask_i,
                        const float* means, const float* stdev,
                        float* patches, unsigned short* tok) {
  int idx = blockIdx.x;
  int b = idx >> 11, pv = idx & 2047, p = pv >> 5, v = pv & 31;
  int bf = flags[0];
  __shared__ float pvs[PL];
  int tid = threadIdx.x;
  float m = means[b * NV + v], sd = stdev[b * NV + v];
  if (tid < PL) {
    float val =
        (ldf(x, (size_t)b * SEQ * NV + (size_t)(p * PL + tid) * NV + v, bf) -
         m) / sd;
    pvs[tid] = val;
    patches[(size_t)idx * PL + tid] = val;
  }
  __syncthreads();
  int masked = mask_i[idx];
  for (int d = tid; d < D; d += 128) {
    float acc = ldf(be, d, bf);
    for (int t = 0; t < PL; t++) acc += pvs[t] * ldf(We, t * D + d, bf);
    tok[(size_t)idx * D + d] = masked ? f2b(0.f) : f2b(acc);
  }
}

// ---------------------------------------------------------------------------
// k_gemm<BM,BN,WN>: C = act(A @ W^T' + bias [+resid]) in bf16. BK=64.
// Linear grid, XCD-swizzled: xcd=id&7 owns a contiguous band of bm-tiles.
// LDS rows are 128B/8-chunk with XOR source-permute swizzle (gll16 forbids
// padding; swizzle balances ds_read_b128 banks).
// ---------------------------------------------------------------------------
template <int BM, int BN, int WN>
__global__ __launch_bounds__(256) void k_gemm(
    const unsigned short* __restrict__ A, const unsigned short* __restrict__ W,
    const float* __restrict__ bias, const unsigned short* __restrict__ resid,
    unsigned short* __restrict__ C, int Nn, int Kk, int act, int nbn) {
  constexpr int FI = 4, FJ = WN / 16, NWN = BN / WN;
  __shared__ __align__(16) char As[BM * 128];   // BM x 64 bf16 (swizzled)
  __shared__ __align__(16) char Bs[BN * 128];   // BN x 64 bf16 (swizzled)
  int tid = threadIdx.x, lane = tid & 63, w = tid >> 6;
  int lane15 = lane & 15, q = lane >> 4;
  int wm = w / NWN, wn = w % NWN;
  int id = blockIdx.x;
  int xcd = id & 7, loc = id >> 3;
  int bn = (loc % nbn) * BN;
  int bm = (xcd * ((int)(gridDim.x >> 3) / nbn) + loc / nbn) * BM;
  int lrow = lane >> 3, lc = lane & 7;
  float4v acc[FI][FJ];
  for (int i = 0; i < FI; i++)
    for (int j = 0; j < FJ; j++) acc[i][j] = 0;
  for (int k0 = 0; k0 < Kk; k0 += 64) {
    if (k0) __syncthreads();
    for (int i = w; i < BM / 8; i += 4) {
      int row = i * 8 + lrow;
      gll16(A + (size_t)(bm + row) * Kk + k0 + ((lc ^ (row & 7)) << 3),
            As + i * 1024);
    }
    for (int i = w; i < BN / 8; i += 4) {
      int row = i * 8 + lrow;
      gll16(W + (size_t)(bn + row) * Kk + k0 + ((lc ^ (row & 7)) << 3),
            Bs + i * 1024);
    }
    __syncthreads();
    short8 a[2][FI], b[2][FJ];
    for (int h = 0; h < 2; h++) {
      for (int i = 0; i < FI; i++) {
        int rr = wm * 64 + i * 16 + lane15;
        a[h][i] =
            *(const short8*)(As + rr * 128 + (((h * 4 + q) ^ (rr & 7)) << 4));
      }
      for (int j = 0; j < FJ; j++) {
        int rr = wn * WN + j * 16 + lane15;
        b[h][j] =
            *(const short8*)(Bs + rr * 128 + (((h * 4 + q) ^ (rr & 7)) << 4));
      }
    }
    for (int h = 0; h < 2; h++)
      for (int i = 0; i < FI; i++)
        for (int j = 0; j < FJ; j++)
          acc[i][j] = __builtin_amdgcn_mfma_f32_16x16x32_bf16(
              a[h][i], b[h][j], acc[i][j], 0, 0, 0);
  }
  for (int i = 0; i < FI; i++) {
    int row = bm + wm * 64 + i * 16 + q * 4;
    for (int j = 0; j < FJ; j++) {
      int col = bn + wn * WN + j * 16 + lane15;
      float bv = bias[col];
      for (int r = 0; r < 4; r++) {
        float cv = acc[i][j][r] + bv;
        size_t off = (size_t)(row + r) * Nn + col;
        if (resid) cv += b2f(resid[off]);
        if (act) cv = 0.5f * cv * (1.f + erff(cv * 0.70710678f));
        C[off] = f2b(cv);
      }
    }
  }
}

// ---------------------------------------------------------------------------
// k_vtrans: vT[(b*512 + hd)][token] = qkv[b*2048+token][1024 + hd].
// 64x64 tile so every 128B line of vT is wholly written by one block.
// ---------------------------------------------------------------------------
__global__ void k_vtrans(const unsigned short* __restrict__ qkv,
                         unsigned short* __restrict__ vT) {
  __shared__ unsigned short tile[64][72];
  int t0 = blockIdx.x * 64, c0 = blockIdx.y * 64, b = blockIdx.z;
  int tid = threadIdx.x;
  int c4 = tid & 15, r = tid >> 4;   // 16 col-quads x 16 rows per pass
  for (int rr = r; rr < 64; rr += 16) {
    ushort4v v = *(const ushort4v*)(qkv + (size_t)(b * 2048 + t0 + rr) * 1536 +
                                    1024 + c0 + c4 * 4);
    *(ushort4v*)(&tile[rr][c4 * 4]) = v;
  }
  __syncthreads();
  for (int rr = r; rr < 64; rr += 16) {
    ushort4v o;
    for (int j = 0; j < 4; j++) o[j] = tile[c4 * 4 + j][rr];
    *(ushort4v*)(vT + (size_t)(b * 512 + c0 + rr) * 2048 + t0 + c4 * 4) = o;
  }
}

// ---------------------------------------------------------------------------
// k_attn: banded MFMA attention. K-window async-staged into LDS (dense
// 128B-line gll16 with XOR chunk swizzle); V fragment-direct from vT with
// register prefetch; vectorized softmax.
// LDS: S strip 32x304 bf16 (19456 B) + Ks 288x64 bf16 (36864 B) = 56320 B.
// ---------------------------------------------------------------------------
__global__ __launch_bounds__(256) void k_attn(
    const unsigned short* __restrict__ qkv,
    const unsigned short* __restrict__ vT, unsigned short* __restrict__ o) {
  constexpr int SSTR = 304;
  constexpr int KS = 32 * SSTR * 2;   // 19456
  __shared__ __align__(16) char sm[KS + 288 * 128];
  unsigned short* S = (unsigned short*)sm;
  int id = blockIdx.x;
  int xcd = id & 7, rr_ = id >> 3;
  int p = xcd * 8 + (rr_ & 7);
  int h = (rr_ >> 3) & 7;
  int b = rr_ >> 6;
  int tid = threadIdx.x, lane = tid & 63, w = tid >> 6;
  int lane15 = lane & 15, q = lane >> 4;
  int p0 = max(0, p - WIN), p1 = min(P - 1, p + WIN);
  int nk = (p1 - p0 + 1) * 32;     // multiple of 32, in [160,288]
  int ntiles = nk >> 4;
  size_t base = (size_t)b * L;
  int mtile = w & 1;
  int lrow = lane >> 3, lc = lane & 7;
  // stage K window into LDS: rows = tokens, 64 el = 128 B dense per row
  {
    const unsigned short* kg = qkv + (base + p0 * 32) * 1536 + 512 + h * 64;
    for (int i = w; i < (nk >> 3); i += 4) {
      int row = i * 8 + lrow;
      gll16(kg + (size_t)row * 1536 + ((lc ^ (row & 7)) << 3),
            sm + KS + i * 1024);
    }
  }
  // Q fragments (A-operand), direct global (independent of staging)
  const unsigned short* qrow =
      qkv + (base + p * 32 + mtile * 16 + lane15) * 1536 + h * 64 + q * 8;
  short8 aq0 = *(const short8*)(qrow);
  short8 aq1 = *(const short8*)(qrow + 32);
  __syncthreads();
  // phase A: S = (Q K^T) * scale from LDS K
  for (int nt = (w >> 1); nt < ntiles; nt += 2) {
    int rr = nt * 16 + lane15;
    const char* krow = sm + KS + rr * 128;
    short8 b0 = *(const short8*)(krow + ((q ^ (rr & 7)) << 4));
    short8 b1 = *(const short8*)(krow + (((4 + q) ^ (rr & 7)) << 4));
    float4v s4 = 0;
    s4 = __builtin_amdgcn_mfma_f32_16x16x32_bf16(aq0, b0, s4, 0, 0, 0);
    s4 = __builtin_amdgcn_mfma_f32_16x16x32_bf16(aq1, b1, s4, 0, 0, 0);
    for (int r = 0; r < 4; r++)
      S[(mtile * 16 + q * 4 + r) * SSTR + nt * 16 + lane15] =
          f2b(s4[r] * 0.125f);
  }
  __syncthreads();
  // phase B: vectorized softmax, 8 threads per row (ushort8 b128 accesses)
  {
    int row = tid >> 3, c = tid & 7;
    float vals[40];
    float mx = -3e38f;
    int cnt = 0;
    for (int k = 0; k < 5; k++) {
      int j0 = c * 8 + k * 64;
      if (j0 < nk) {
        ushort8 u = *(const ushort8*)(S + row * SSTR + j0);
        for (int t = 0; t < 8; t++) {
          float v = b2f(u[t]);
          vals[cnt++] = v;
          mx = fmaxf(mx, v);
        }
      }
    }
    for (int off = 1; off < 8; off <<= 1) mx = fmaxf(mx, __shfl_xor(mx, off));
    float sum = 0.f;
    for (int t = 0; t < cnt; t++) {
      float e = __expf(vals[t] - mx);
      vals[t] = e; sum += e;
    }
    for (int off = 1; off < 8; off <<= 1) sum += __shfl_xor(sum, off);
    float inv = 1.f / sum;
    cnt = 0;
    for (int k = 0; k < 5; k++) {
      int j0 = c * 8 + k * 64;
      if (j0 < nk) {
        ushort8 u;
        for (int t = 0; t < 8; t++) u[t] = f2b(vals[cnt++] * inv);
        *(ushort8*)(S + row * SSTR + j0) = u;
      }
    }
  }
  __syncthreads();
  // phase C: O = P V, V fragment-direct from vT with register prefetch
  int ntb = (w >> 1) * 2;
  int nkt = nk >> 5;
  const unsigned short* vb0 =
      vT + (size_t)(b * 512 + h * 64 + ntb * 16 + lane15) * 2048 + p0 * 32 +
      q * 8;
  const unsigned short* vb1 = vb0 + 16 * 2048;
  const unsigned short* prow = S + (mtile * 16 + lane15) * SSTR + q * 8;
  float4v oa0 = 0, oa1 = 0;
  short8 ap = *(const short8*)(prow);
  short8 v0 = *(const short8*)(vb0);
  short8 v1 = *(const short8*)(vb1);
  for (int kt = 0; kt < nkt; kt++) {
    short8 apN, v0N, v1N;
    if (kt + 1 < nkt) {
      apN = *(const short8*)(prow + (kt + 1) * 32);
      v0N = *(const short8*)(vb0 + (kt + 1) * 32);
      v1N = *(const short8*)(vb1 + (kt + 1) * 32);
    }
    oa0 = __builtin_amdgcn_mfma_f32_16x16x32_bf16(ap, v0, oa0, 0, 0, 0);
    oa1 = __builtin_amdgcn_mfma_f32_16x16x32_bf16(ap, v1, oa1, 0, 0, 0);
    ap = apN; v0 = v0N; v1 = v1N;
  }
  // stage O in LDS (reuse S), then store full 128B lines cooperatively
  __syncthreads();
  for (int r = 0; r < 4; r++) {
    S[(mtile * 16 + q * 4 + r) * 72 + ntb * 16 + lane15] = f2b(oa0[r]);
    S[(mtile * 16 + q * 4 + r) * 72 + (ntb + 1) * 16 + lane15] = f2b(oa1[r]);
  }
  __syncthreads();
  {
    int row = tid >> 3, c8 = tid & 7;
    ushort8 val = *(const ushort8*)(S + row * 72 + c8 * 8);
    *(ushort8*)(o + (base + p * 32 + row) * 512 + h * 64 + c8 * 8) = val;
  }
}

// ---------------------------------------------------------------------------
// k_ln: layernorm over D=512 per token, bf16 in/out. 4 rows per block.
// ---------------------------------------------------------------------------
__global__ void k_ln(const unsigned short* __restrict__ x, const void* g,
                     const void* bta, unsigned short* __restrict__ out,
                     const int* flags, int goff) {
  int bf = flags[0];
  int row = blockIdx.x * 4 + (threadIdx.x >> 6);
  int lane = threadIdx.x & 63;
  ushort8 u = *(const ushort8*)(x + (size_t)row * D + lane * 8);
  float v[8]; float s = 0.f, s2 = 0.f;
  for (int t = 0; t < 8; t++) {
    v[t] = b2f(u[t]); s += v[t]; s2 += v[t] * v[t];
  }
  for (int off = 32; off; off >>= 1) {
    s += __shfl_xor(s, off); s2 += __shfl_xor(s2, off);
  }
  float m = s / (float)D;
  float inv = rsqrtf(s2 / (float)D - m * m + 1e-5f);
  ushort8 ou;
  for (int t = 0; t < 8; t++) {
    int c = lane * 8 + t;
    ou[t] = f2b((v[t] - m) * inv * ldf(g, goff + c, bf) + ldf(bta, goff + c, bf));
  }
  *(ushort8*)(out + (size_t)row * D + lane * 8) = ou;
}

// ---------------------------------------------------------------------------
// k_lnloss: fused final LN + recon head (MFMA) + masked MSE.
// ---------------------------------------------------------------------------
__global__ __launch_bounds__(128) void k_lnloss(
    const unsigned short* __restrict__ tok, const float* __restrict__ lnw,
    const unsigned short* __restrict__ WpT, const float* __restrict__ patches,
    const float* __restrict__ stdev, const int* __restrict__ mask_i,
    float* scal) {
  constexpr int RS = 520;  // padded LDS row stride (elements)
  __shared__ __align__(16) unsigned short As[32 * RS];
  __shared__ __align__(16) unsigned short Bs[16 * RS];
  int bpI = blockIdx.x; int b = bpI >> 6, p = bpI & 63;
  int tid = threadIdx.x;
  int row = tid >> 2, cg = tid & 3;   // 4 threads per token row
  size_t tokbase = (size_t)(b * L + p * 32);
  float s = 0.f, s2 = 0.f;
  for (int i = 0; i < 16; i++) {
    int c = cg + i * 4;
    ushort8 u = *(const ushort8*)(tok + (tokbase + row) * D + c * 8);
    for (int t = 0; t < 8; t++) { float v = b2f(u[t]); s += v; s2 += v * v; }
  }
  s += __shfl_xor(s, 1); s += __shfl_xor(s, 2);
  s2 += __shfl_xor(s2, 1); s2 += __shfl_xor(s2, 2);
  float m = s / (float)D;
  float inv = rsqrtf(s2 / (float)D - m * m + 1e-5f);
  for (int i = 0; i < 16; i++) {
    int c = cg + i * 4;
    ushort8 u = *(const ushort8*)(tok + (tokbase + row) * D + c * 8);
    ushort8 o;
    for (int t = 0; t < 8; t++) {
      int col = c * 8 + t;
      o[t] = f2b((b2f(u[t]) - m) * inv * lnw[col] + lnw[512 + col]);
    }
    *(ushort8*)(As + row * RS + c * 8) = o;
  }
  for (int e = tid; e < 16 * 64; e += 128) {
    int r = e >> 6, c = e & 63;
    *(ushort8*)(Bs + r * RS + c * 8) = *(const ushort8*)(WpT + r * 512 + c * 8);
  }
  __syncthreads();
  int w = tid >> 6, lane = tid & 63, lane15 = lane & 15, q = lane >> 4;
  float4v acc = 0;
  for (int kt = 0; kt < 16; kt++) {
    short8 a = *(const short8*)(As + (w * 16 + lane15) * RS + kt * 32 + q * 8);
    short8 bfr = *(const short8*)(Bs + lane15 * RS + kt * 32 + q * 8);
    acc = __builtin_amdgcn_mfma_f32_16x16x32_bf16(a, bfr, acc, 0, 0, 0);
  }
  float local = 0.f;
  int t = lane15;
  for (int r = 0; r < 4; r++) {
    int v = w * 16 + q * 4 + r;
    int tokidx = b * 2048 + p * 32 + v;
    if (mask_i[tokidx]) {
      float recon = acc[r] + lnw[1024 + t];
      float diff = recon - patches[(size_t)tokidx * 16 + t];
      float sc = stdev[b * 32 + v];
      local += sc * sc * diff * diff;
    }
  }
  for (int off = 32; off; off >>= 1) local += __shfl_xor(local, off);
  if (lane == 0) atomicAdd(&scal[0], local);
}

__global__ void k_final(const float* scal, const int* flags, unsigned* out) {
  float denom = (float)flags[1] * (float)PL;
  if (denom == 0.f) denom = 1.f;
  float loss = scal[0] / denom;
  unsigned fb = __float_as_uint(loss);
  unsigned u = (fb + 0x7FFFu + ((fb >> 16) & 1u)) >> 16;
  out[0] = (u << 16) | u;
}

}  // namespace

extern "C" void kernel_launch(void* const* d_in, const int* in_sizes, int n_in,
                              void* d_out, int out_size, void* d_ws,
                              size_t ws_size, hipStream_t stream) {
  const void* x_enc = d_in[0];
  const void* maskp = d_in[1];
  const void* We = d_in[2];  const void* be_ = d_in[3];
  const void* Wq = d_in[4];  const void* bq = d_in[5];
  const void* Wk = d_in[6];  const void* bk = d_in[7];
  const void* Wv = d_in[8];  const void* bv = d_in[9];
  const void* Wo = d_in[10]; const void* bo_ = d_in[11];
  const void* W1 = d_in[12]; const void* b1 = d_in[13];
  const void* W2 = d_in[14]; const void* b2 = d_in[15];
  const void* g1 = d_in[16]; const void* be1 = d_in[17];
  const void* g2 = d_in[18]; const void* be2 = d_in[19];
  const void* gf = d_in[20]; const void* bff = d_in[21];
  const void* Wp = d_in[22]; const void* bp = d_in[23];

  constexpr size_t MB = 1u << 20;
  char* w = (char*)d_ws;
  int*   mask_i  = (int*)w;                        // 32 KB
  int*   flags   = (int*)(w + 32768);
  float* scal    = (float*)(w + 32896);
  float* means   = (float*)(w + 33024);
  float* stdev   = (float*)(w + 33600);
  float* biasf   = (float*)(w + 36864);            // 73728 B -> ends 110592
  float* lnw     = (float*)(w + 114688);           // 4160 B
  float* patches = (float*)(w + 131072);           // 512 KB -> ends 655360
  unsigned short* WpT = (unsigned short*)(w + 655360);    // 16 KB
  unsigned short* qkvT = (unsigned short*)(w + 1 * MB);   // 6 MB
  unsigned short* WoT  = (unsigned short*)(w + 7 * MB);   // 2 MB
  unsigned short* W1T  = (unsigned short*)(w + 9 * MB);   // 8 MB
  unsigned short* W2T  = (unsigned short*)(w + 17 * MB);  // 8 MB
  unsigned short* tok  = (unsigned short*)(w + 25 * MB);  // 8 MB
  unsigned short* tmp  = (unsigned short*)(w + 33 * MB);  // 8 MB
  unsigned short* ob   = (unsigned short*)(w + 41 * MB);  // 8 MB
  unsigned short* qkv  = (unsigned short*)(w + 49 * MB);  // 24 MB -> ends 73
  unsigned short* vTb  = (unsigned short*)(w + 73 * MB);  // 8 MB -> ends 81
  unsigned short* hidden = ob;   // 32 MB alias over ob+qkv (dead by FFN1)

  k_setup<<<1, 256, 0, stream>>>(gf, maskp, mask_i, flags, scal);
  k_prep<<<141, 256, 0, stream>>>(x_enc, bq, bk, bv, bo_, b1, b2, gf, bff, Wp,
                                  bp, flags, means, stdev, biasf, lnw, WpT);
  k_transpose_all<<<12288, 256, 0, stream>>>(Wq, Wk, Wv, Wo, W1, W2, qkvT, WoT,
                                             W1T, W2T, flags);
  k_embed<<<M, 128, 0, stream>>>(x_enc, We, be_, flags, mask_i, means, stdev,
                                 patches, tok);
  for (int l = 0; l < 4; l++) {
    k_gemm<128, 128, 64><<<768, 256, 0, stream>>>(
        tok, qkvT + (size_t)l * 786432, biasf + l * 1536, nullptr, qkv, 1536,
        512, 0, 12);
    k_vtrans<<<dim3(32, 8, 4), 256, 0, stream>>>(qkv, vTb);
    k_attn<<<2048, 256, 0, stream>>>(qkv, vTb, ob);
    k_gemm<128, 64, 32><<<512, 256, 0, stream>>>(
        ob, WoT + (size_t)l * 262144, biasf + 6144 + l * 512, tok, tmp, 512,
        512, 0, 8);
    k_ln<<<M / 4, 256, 0, stream>>>(tmp, g1, be1, tok, flags, l * 512);
    k_gemm<128, 128, 64><<<1024, 256, 0, stream>>>(
        tok, W1T + (size_t)l * 1048576, biasf + 8192 + l * 2048, nullptr,
        hidden, 2048, 512, 1, 16);
    k_gemm<128, 64, 32><<<512, 256, 0, stream>>>(
        hidden, W2T + (size_t)l * 1048576, biasf + 16384 + l * 512, tok, tmp,
        512, 2048, 0, 8);
    k_ln<<<M / 4, 256, 0, stream>>>(tmp, g2, be2, tok, flags, l * 512);
  }
  k_lnloss<<<Bn * P, 128, 0, stream>>>(tok, lnw, WpT, patches, stdev, mask_i,
                                       scal);
  k_final<<<1, 1, 0, stream>>>(scal, flags, (unsigned*)d_out);
}

// Round 8
// 1089.619 us; speedup vs baseline: 1.1177x; 1.1177x over previous
//
#include <hip/hip_runtime.h>
#include <hip/hip_bf16.h>

#define DEV __device__ __forceinline__

namespace {

constexpr int Bn  = 4, SEQ = 1024, NV = 32, PL = 16, D = 512, H = 8, DFF = 2048;
constexpr int P   = SEQ / PL;    // 64 patches
constexpr int L   = P * NV;      // 2048 tokens per batch
constexpr int M   = Bn * L;      // 8192 total token rows
constexpr int WIN = 4;

using short8   = __attribute__((ext_vector_type(8))) short;
using ushort8  = __attribute__((ext_vector_type(8))) unsigned short;
using ushort4v = __attribute__((ext_vector_type(4))) unsigned short;
using float4v  = __attribute__((ext_vector_type(4))) float;

DEV float b2f(unsigned short u) { return __uint_as_float(((unsigned)u) << 16); }
DEV unsigned short f2b(float f) {
  unsigned fb = __float_as_uint(f);
  return (unsigned short)((fb + 0x7FFFu + ((fb >> 16) & 1u)) >> 16);
}
// flag-dispatched float load from an input tensor: bf=1 -> bf16, 0 -> fp32
DEV float ldf(const void* p, size_t idx, int bf) {
  if (bf) return b2f(((const unsigned short*)p)[idx]);
  return ((const float*)p)[idx];
}
// async global->LDS 16B: lds dest = wave-uniform base + lane*16
DEV void gll16(const void* gp, void* lp) {
  __builtin_amdgcn_global_load_lds(
      (const __attribute__((address_space(1))) void*)gp,
      (__attribute__((address_space(3))) void*)lp, 16, 0, 0);
}

// ---------------------------------------------------------------------------
// k_setup: detect float dtype + mask format, canonicalize mask, count masked.
// ---------------------------------------------------------------------------
__global__ void k_setup(const void* gf, const void* mask_raw, int* mask_i,
                        int* flags, float* scal) {
  __shared__ int s_gt1, s_oth, s_cnt;
  int tid = threadIdx.x;
  if (tid == 0) { s_gt1 = 0; s_oth = 0; s_cnt = 0; }
  __syncthreads();
  const unsigned* mw = (const unsigned*)mask_raw;
  int gt1 = 0, oth = 0;
  for (int i = tid; i < 2048; i += 256) {
    unsigned w = mw[i];
    if (w > 1u) { gt1 = 1; if (w != 0x3F800000u) oth = 1; }
  }
  if (gt1) atomicOr(&s_gt1, 1);
  if (oth) atomicOr(&s_oth, 1);
  __syncthreads();
  int fmt = (!s_gt1) ? 0 : (!s_oth ? 1 : 2);  // 0=int32, 1=f32, 2=bytes
  int cnt = 0;
  for (int i = tid; i < Bn * P * NV; i += 256) {
    int m;
    if (fmt == 0)      m = ((const int*)mask_raw)[i] != 0;
    else if (fmt == 1) m = ((const float*)mask_raw)[i] != 0.0f;
    else               m = ((const unsigned char*)mask_raw)[i] != 0;
    mask_i[i] = m; cnt += m;
  }
  atomicAdd(&s_cnt, cnt);
  __syncthreads();
  if (tid == 0) {
    unsigned w = *(const unsigned*)gf;
    flags[0] = ((w & 0xFFFFu) == 0x3F80u) ? 1 : 0;
    flags[1] = s_cnt;
    scal[0] = 0.f;
  }
}

// ---------------------------------------------------------------------------
// k_prep: blocks 0..31 -> per-(b,v) stats; blocks 32.. -> gather biases,
// final-LN weights (fp32), b_proj (fp32), and WpT (bf16 [t][d]).
// ---------------------------------------------------------------------------
__global__ void k_prep(const void* x, const void* bq, const void* bk,
                       const void* bv, const void* bo, const void* b1,
                       const void* b2, const void* gf, const void* bff,
                       const void* Wp, const void* bp, const int* flags,
                       float* means, float* stdev, float* biasf, float* lnw,
                       unsigned short* WpT) {
  int bf = flags[0];
  int tid = threadIdx.x;
  if (blockIdx.x < 32) {
    int bv_ = blockIdx.x * 4 + (tid >> 6);
    int b = bv_ >> 5, v = bv_ & 31;
    int lane = tid & 63;
    float s = 0.f, s2 = 0.f;
    for (int t = lane; t < SEQ; t += 64) {
      float val = ldf(x, (size_t)b * SEQ * NV + (size_t)t * NV + v, bf);
      s += val; s2 += val * val;
    }
    for (int off = 32; off; off >>= 1) {
      s += __shfl_xor(s, off); s2 += __shfl_xor(s2, off);
    }
    if (lane == 0) {
      float m = s / (float)SEQ;
      means[bv_] = m;
      stdev[bv_] = sqrtf(s2 / (float)SEQ - m * m + 1e-5f);
    }
    return;
  }
  int i = (blockIdx.x - 32) * 256 + tid;
  if (i < 18432) {
    int l = i / 4608, r = i % 4608;
    if (r < 1536) {
      float v = (r < 512) ? ldf(bq, l * 512 + r, bf)
              : (r < 1024) ? ldf(bk, l * 512 + r - 512, bf)
                           : ldf(bv, l * 512 + r - 1024, bf);
      biasf[l * 1536 + r] = v;
    } else if (r < 2048) {
      biasf[6144 + l * 512 + (r - 1536)] = ldf(bo, l * 512 + r - 1536, bf);
    } else if (r < 4096) {
      biasf[8192 + l * 2048 + (r - 2048)] = ldf(b1, l * 2048 + r - 2048, bf);
    } else {
      biasf[16384 + l * 512 + (r - 4096)] = ldf(b2, l * 512 + r - 4096, bf);
    }
  } else if (i < 19456) {
    int j = i - 18432;
    lnw[j] = (j < 512) ? ldf(gf, j, bf) : ldf(bff, j - 512, bf);
  } else if (i < 19472) {
    lnw[1024 + (i - 19456)] = ldf(bp, i - 19456, bf);
  } else if (i < 27664) {
    int j = i - 19472; int t = j >> 9, d = j & 511;
    WpT[j] = f2b(ldf(Wp, d * 16 + t, bf));
  }
}

// ---------------------------------------------------------------------------
// k_transpose_all: all 6 weight transposes in one dispatch.
// dst[l][n][k] (bf16) = src[l][k][n]. 32x32 LDS tile per block.
// ---------------------------------------------------------------------------
__global__ void k_transpose_all(const void* Wq, const void* Wk, const void* Wv,
                                const void* Wo, const void* W1, const void* W2,
                                unsigned short* qkvT, unsigned short* WoT,
                                unsigned short* W1T, unsigned short* W2T,
                                const int* flags) {
  int bf = flags[0];
  int id = blockIdx.x;
  const void* src; unsigned short* dst;
  int Kd, Nd, l, n0, k0, dstOff = 0;
  size_t srcLS, dstLS;
  if (id < 4096) {
    int tensor = id >> 10, rem = id & 1023;
    l = rem >> 8; int t = rem & 255;
    n0 = (t & 15) * 32; k0 = (t >> 4) * 32;
    Kd = 512; Nd = 512; srcLS = 262144;
    if (tensor == 0)      { src = Wq; dst = qkvT; dstLS = 786432; dstOff = 0; }
    else if (tensor == 1) { src = Wk; dst = qkvT; dstLS = 786432; dstOff = 262144; }
    else if (tensor == 2) { src = Wv; dst = qkvT; dstLS = 786432; dstOff = 524288; }
    else                  { src = Wo; dst = WoT;  dstLS = 262144; }
  } else if (id < 8192) {
    int rem = id - 4096; l = rem >> 10; int t = rem & 1023;
    n0 = (t & 63) * 32; k0 = (t >> 6) * 32;
    Kd = 512; Nd = 2048; srcLS = 1048576; src = W1; dst = W1T; dstLS = 1048576;
  } else {
    int rem = id - 8192; l = rem >> 10; int t = rem & 1023;
    n0 = (t & 15) * 32; k0 = (t >> 4) * 32;
    Kd = 2048; Nd = 512; srcLS = 1048576; src = W2; dst = W2T; dstLS = 1048576;
  }
  int tx = threadIdx.x & 31, ty = threadIdx.x >> 5;
  __shared__ float tile[32][33];
  for (int rr = ty; rr < 32; rr += 8)
    tile[rr][tx] =
        ldf(src, (size_t)l * srcLS + (size_t)(k0 + rr) * Nd + n0 + tx, bf);
  __syncthreads();
  for (int rr = ty; rr < 32; rr += 8)
    dst[(size_t)l * dstLS + dstOff + (size_t)(n0 + rr) * Kd + k0 + tx] =
        f2b(tile[tx][rr]);
}

// ---------------------------------------------------------------------------
// k_embed: patchify + instance-normalize, write patches (fp32) and embedded
// tokens (bf16), zeroing masked tokens. One block (128 thr) per token.
// ---------------------------------------------------------------------------
__global__ void k_embed(const void* x, const void* We, const void* be,
                        const int* flags, const int* mask_i,
                        const float* means, const float* stdev,
                        float* patches, unsigned short* tok) {
  int idx = blockIdx.x;
  int b = idx >> 11, pv = idx & 2047, p = pv >> 5, v = pv & 31;
  int bf = flags[0];
  __shared__ float pvs[PL];
  int tid = threadIdx.x;
  float m = means[b * NV + v], sd = stdev[b * NV + v];
  if (tid < PL) {
    float val =
        (ldf(x, (size_t)b * SEQ * NV + (size_t)(p * PL + tid) * NV + v, bf) -
         m) / sd;
    pvs[tid] = val;
    patches[(size_t)idx * PL + tid] = val;
  }
  __syncthreads();
  int masked = mask_i[idx];
  for (int d = tid; d < D; d += 128) {
    float acc = ldf(be, d, bf);
    for (int t = 0; t < PL; t++) acc += pvs[t] * ldf(We, t * D + d, bf);
    tok[(size_t)idx * D + d] = masked ? f2b(0.f) : f2b(acc);
  }
}

// ---------------------------------------------------------------------------
// k_gemm<BM,BN,WN>: C = act(A @ W^T' + bias [+resid]) in bf16. BK=64.
// Linear grid, XCD-swizzled: xcd=id&7 owns a contiguous band of bm-tiles.
// LDS rows are 128B/8-chunk with XOR source-permute swizzle (gll16 forbids
// padding; swizzle balances ds_read_b128 banks).
// ---------------------------------------------------------------------------
template <int BM, int BN, int WN>
__global__ __launch_bounds__(256) void k_gemm(
    const unsigned short* __restrict__ A, const unsigned short* __restrict__ W,
    const float* __restrict__ bias, const unsigned short* __restrict__ resid,
    unsigned short* __restrict__ C, int Nn, int Kk, int act, int nbn) {
  constexpr int FI = 4, FJ = WN / 16, NWN = BN / WN;
  __shared__ __align__(16) char As[BM * 128];   // BM x 64 bf16 (swizzled)
  __shared__ __align__(16) char Bs[BN * 128];   // BN x 64 bf16 (swizzled)
  int tid = threadIdx.x, lane = tid & 63, w = tid >> 6;
  int lane15 = lane & 15, q = lane >> 4;
  int wm = w / NWN, wn = w % NWN;
  int id = blockIdx.x;
  int xcd = id & 7, loc = id >> 3;
  int bn = (loc % nbn) * BN;
  int bm = (xcd * ((int)(gridDim.x >> 3) / nbn) + loc / nbn) * BM;
  int lrow = lane >> 3, lc = lane & 7;
  float4v acc[FI][FJ];
  for (int i = 0; i < FI; i++)
    for (int j = 0; j < FJ; j++) acc[i][j] = 0;
  for (int k0 = 0; k0 < Kk; k0 += 64) {
    if (k0) __syncthreads();
    for (int i = w; i < BM / 8; i += 4) {
      int row = i * 8 + lrow;
      gll16(A + (size_t)(bm + row) * Kk + k0 + ((lc ^ (row & 7)) << 3),
            As + i * 1024);
    }
    for (int i = w; i < BN / 8; i += 4) {
      int row = i * 8 + lrow;
      gll16(W + (size_t)(bn + row) * Kk + k0 + ((lc ^ (row & 7)) << 3),
            Bs + i * 1024);
    }
    __syncthreads();
    short8 a[2][FI], b[2][FJ];
    for (int h = 0; h < 2; h++) {
      for (int i = 0; i < FI; i++) {
        int rr = wm * 64 + i * 16 + lane15;
        a[h][i] =
            *(const short8*)(As + rr * 128 + (((h * 4 + q) ^ (rr & 7)) << 4));
      }
      for (int j = 0; j < FJ; j++) {
        int rr = wn * WN + j * 16 + lane15;
        b[h][j] =
            *(const short8*)(Bs + rr * 128 + (((h * 4 + q) ^ (rr & 7)) << 4));
      }
    }
    for (int h = 0; h < 2; h++)
      for (int i = 0; i < FI; i++)
        for (int j = 0; j < FJ; j++)
          acc[i][j] = __builtin_amdgcn_mfma_f32_16x16x32_bf16(
              a[h][i], b[h][j], acc[i][j], 0, 0, 0);
  }
  for (int i = 0; i < FI; i++) {
    int row = bm + wm * 64 + i * 16 + q * 4;
    for (int j = 0; j < FJ; j++) {
      int col = bn + wn * WN + j * 16 + lane15;
      float bv = bias[col];
      for (int r = 0; r < 4; r++) {
        float cv = acc[i][j][r] + bv;
        size_t off = (size_t)(row + r) * Nn + col;
        if (resid) cv += b2f(resid[off]);
        if (act) cv = 0.5f * cv * (1.f + erff(cv * 0.70710678f));
        C[off] = f2b(cv);
      }
    }
  }
}

// ---------------------------------------------------------------------------
// k_vtrans: vT[(b*512 + hd)][token] = qkv[b*2048+token][1024 + hd].
// 64x64 tile so every 128B line of vT is wholly written by one block.
// ---------------------------------------------------------------------------
__global__ void k_vtrans(const unsigned short* __restrict__ qkv,
                         unsigned short* __restrict__ vT) {
  __shared__ unsigned short tile[64][72];
  int t0 = blockIdx.x * 64, c0 = blockIdx.y * 64, b = blockIdx.z;
  int tid = threadIdx.x;
  int c4 = tid & 15, r = tid >> 4;   // 16 col-quads x 16 rows per pass
  for (int rr = r; rr < 64; rr += 16) {
    ushort4v v = *(const ushort4v*)(qkv + (size_t)(b * 2048 + t0 + rr) * 1536 +
                                    1024 + c0 + c4 * 4);
    *(ushort4v*)(&tile[rr][c4 * 4]) = v;
  }
  __syncthreads();
  for (int rr = r; rr < 64; rr += 16) {
    ushort4v o;
    for (int j = 0; j < 4; j++) o[j] = tile[c4 * 4 + j][rr];
    *(ushort4v*)(vT + (size_t)(b * 512 + c0 + rr) * 2048 + t0 + c4 * 4) = o;
  }
}

// ---------------------------------------------------------------------------
// k_attn: banded MFMA attention, fragment-direct global loads (R6 version:
// 19.5 KB LDS, VGPR ~20 -> 8 blocks/CU. R7's LDS K-staging (56 KB) dropped
// occupancy to 2 blocks/CU and regressed 62->100 us. Keep <=20KB LDS and
// <=64 VGPR here.)
// ---------------------------------------------------------------------------
__global__ __launch_bounds__(256) void k_attn(
    const unsigned short* __restrict__ qkv,
    const unsigned short* __restrict__ vT, unsigned short* __restrict__ o) {
  constexpr int SSTR = 304;
  __shared__ __align__(16) unsigned short S[32 * SSTR];
  int id = blockIdx.x;
  int xcd = id & 7, rr_ = id >> 3;
  int p = xcd * 8 + (rr_ & 7);
  int h = (rr_ >> 3) & 7;
  int b = rr_ >> 6;
  int tid = threadIdx.x, lane = tid & 63, w = tid >> 6;
  int lane15 = lane & 15, q = lane >> 4;
  int p0 = max(0, p - WIN), p1 = min(P - 1, p + WIN);
  int nk = (p1 - p0 + 1) * 32;     // multiple of 32, in [160,288]
  int ntiles = nk >> 4;
  size_t base = (size_t)b * L;
  int mtile = w & 1;
  // Q fragments (A-operand), direct global
  const unsigned short* qrow =
      qkv + (base + p * 32 + mtile * 16 + lane15) * 1536 + h * 64 + q * 8;
  short8 aq0 = *(const short8*)(qrow);
  short8 aq1 = *(const short8*)(qrow + 32);
  // phase A: S = (Q K^T) * scale, bf16 into LDS
  const unsigned short* kbase =
      qkv + (base + p0 * 32) * 1536 + 512 + h * 64 + q * 8;
  for (int nt = (w >> 1); nt < ntiles; nt += 2) {
    const unsigned short* krow = kbase + (size_t)(nt * 16 + lane15) * 1536;
    short8 b0 = *(const short8*)(krow);
    short8 b1 = *(const short8*)(krow + 32);
    float4v s4 = 0;
    s4 = __builtin_amdgcn_mfma_f32_16x16x32_bf16(aq0, b0, s4, 0, 0, 0);
    s4 = __builtin_amdgcn_mfma_f32_16x16x32_bf16(aq1, b1, s4, 0, 0, 0);
    for (int r = 0; r < 4; r++)
      S[(mtile * 16 + q * 4 + r) * SSTR + nt * 16 + lane15] =
          f2b(s4[r] * 0.125f);
  }
  __syncthreads();
  // phase B: softmax, 8 threads per row, P bf16 in place
  {
    int row = tid >> 3, c = tid & 7;
    float mx = -3e38f;
    for (int j = c; j < nk; j += 8) mx = fmaxf(mx, b2f(S[row * SSTR + j]));
    for (int off = 1; off < 8; off <<= 1) mx = fmaxf(mx, __shfl_xor(mx, off));
    float sum = 0.f;
    float ev[36];
    int cnt = 0;
    for (int j = c; j < nk; j += 8) {
      float e = __expf(b2f(S[row * SSTR + j]) - mx);
      ev[cnt++] = e; sum += e;
    }
    for (int off = 1; off < 8; off <<= 1) sum += __shfl_xor(sum, off);
    float inv = 1.f / sum;
    cnt = 0;
    for (int j = c; j < nk; j += 8) S[row * SSTR + j] = f2b(ev[cnt++] * inv);
  }
  __syncthreads();
  // phase C: O = P V, V fragments direct from vT (contiguous along tokens)
  int ntb = (w >> 1) * 2;
  float4v oa[2]; oa[0] = 0; oa[1] = 0;
  for (int kt = 0; kt < (nk >> 5); kt++) {
    short8 ap = *(const short8*)(S + (mtile * 16 + lane15) * SSTR + kt * 32 +
                                 q * 8);
    for (int jj = 0; jj < 2; jj++) {
      const unsigned short* vrow =
          vT + (size_t)(b * 512 + h * 64 + (ntb + jj) * 16 + lane15) * 2048 +
          p0 * 32 + kt * 32 + q * 8;
      short8 bv = *(const short8*)(vrow);
      oa[jj] = __builtin_amdgcn_mfma_f32_16x16x32_bf16(ap, bv, oa[jj], 0, 0, 0);
    }
  }
  // stage O in LDS (reuse S), then store full 128B lines cooperatively
  __syncthreads();
  for (int jj = 0; jj < 2; jj++)
    for (int r = 0; r < 4; r++)
      S[(mtile * 16 + q * 4 + r) * 72 + (ntb + jj) * 16 + lane15] =
          f2b(oa[jj][r]);
  __syncthreads();
  {
    int row = tid >> 3, c8 = tid & 7;
    ushort8 val = *(const ushort8*)(S + row * 72 + c8 * 8);
    *(ushort8*)(o + (base + p * 32 + row) * 512 + h * 64 + c8 * 8) = val;
  }
}

// ---------------------------------------------------------------------------
// k_ln: layernorm over D=512 per token, bf16 in/out. 4 rows per block.
// ---------------------------------------------------------------------------
__global__ void k_ln(const unsigned short* __restrict__ x, const void* g,
                     const void* bta, unsigned short* __restrict__ out,
                     const int* flags, int goff) {
  int bf = flags[0];
  int row = blockIdx.x * 4 + (threadIdx.x >> 6);
  int lane = threadIdx.x & 63;
  ushort8 u = *(const ushort8*)(x + (size_t)row * D + lane * 8);
  float v[8]; float s = 0.f, s2 = 0.f;
  for (int t = 0; t < 8; t++) {
    v[t] = b2f(u[t]); s += v[t]; s2 += v[t] * v[t];
  }
  for (int off = 32; off; off >>= 1) {
    s += __shfl_xor(s, off); s2 += __shfl_xor(s2, off);
  }
  float m = s / (float)D;
  float inv = rsqrtf(s2 / (float)D - m * m + 1e-5f);
  ushort8 ou;
  for (int t = 0; t < 8; t++) {
    int c = lane * 8 + t;
    ou[t] = f2b((v[t] - m) * inv * ldf(g, goff + c, bf) + ldf(bta, goff + c, bf));
  }
  *(ushort8*)(out + (size_t)row * D + lane * 8) = ou;
}

// ---------------------------------------------------------------------------
// k_lnloss: fused final LN + recon head (MFMA) + masked MSE.
// ---------------------------------------------------------------------------
__global__ __launch_bounds__(128) void k_lnloss(
    const unsigned short* __restrict__ tok, const float* __restrict__ lnw,
    const unsigned short* __restrict__ WpT, const float* __restrict__ patches,
    const float* __restrict__ stdev, const int* __restrict__ mask_i,
    float* scal) {
  constexpr int RS = 520;  // padded LDS row stride (elements)
  __shared__ __align__(16) unsigned short As[32 * RS];
  __shared__ __align__(16) unsigned short Bs[16 * RS];
  int bpI = blockIdx.x; int b = bpI >> 6, p = bpI & 63;
  int tid = threadIdx.x;
  int row = tid >> 2, cg = tid & 3;   // 4 threads per token row
  size_t tokbase = (size_t)(b * L + p * 32);
  float s = 0.f, s2 = 0.f;
  for (int i = 0; i < 16; i++) {
    int c = cg + i * 4;
    ushort8 u = *(const ushort8*)(tok + (tokbase + row) * D + c * 8);
    for (int t = 0; t < 8; t++) { float v = b2f(u[t]); s += v; s2 += v * v; }
  }
  s += __shfl_xor(s, 1); s += __shfl_xor(s, 2);
  s2 += __shfl_xor(s2, 1); s2 += __shfl_xor(s2, 2);
  float m = s / (float)D;
  float inv = rsqrtf(s2 / (float)D - m * m + 1e-5f);
  for (int i = 0; i < 16; i++) {
    int c = cg + i * 4;
    ushort8 u = *(const ushort8*)(tok + (tokbase + row) * D + c * 8);
    ushort8 o;
    for (int t = 0; t < 8; t++) {
      int col = c * 8 + t;
      o[t] = f2b((b2f(u[t]) - m) * inv * lnw[col] + lnw[512 + col]);
    }
    *(ushort8*)(As + row * RS + c * 8) = o;
  }
  for (int e = tid; e < 16 * 64; e += 128) {
    int r = e >> 6, c = e & 63;
    *(ushort8*)(Bs + r * RS + c * 8) = *(const ushort8*)(WpT + r * 512 + c * 8);
  }
  __syncthreads();
  int w = tid >> 6, lane = tid & 63, lane15 = lane & 15, q = lane >> 4;
  float4v acc = 0;
  for (int kt = 0; kt < 16; kt++) {
    short8 a = *(const short8*)(As + (w * 16 + lane15) * RS + kt * 32 + q * 8);
    short8 bfr = *(const short8*)(Bs + lane15 * RS + kt * 32 + q * 8);
    acc = __builtin_amdgcn_mfma_f32_16x16x32_bf16(a, bfr, acc, 0, 0, 0);
  }
  float local = 0.f;
  int t = lane15;
  for (int r = 0; r < 4; r++) {
    int v = w * 16 + q * 4 + r;
    int tokidx = b * 2048 + p * 32 + v;
    if (mask_i[tokidx]) {
      float recon = acc[r] + lnw[1024 + t];
      float diff = recon - patches[(size_t)tokidx * 16 + t];
      float sc = stdev[b * 32 + v];
      local += sc * sc * diff * diff;
    }
  }
  for (int off = 32; off; off >>= 1) local += __shfl_xor(local, off);
  if (lane == 0) atomicAdd(&scal[0], local);
}

__global__ void k_final(const float* scal, const int* flags, unsigned* out) {
  float denom = (float)flags[1] * (float)PL;
  if (denom == 0.f) denom = 1.f;
  float loss = scal[0] / denom;
  unsigned fb = __float_as_uint(loss);
  unsigned u = (fb + 0x7FFFu + ((fb >> 16) & 1u)) >> 16;
  out[0] = (u << 16) | u;
}

}  // namespace

extern "C" void kernel_launch(void* const* d_in, const int* in_sizes, int n_in,
                              void* d_out, int out_size, void* d_ws,
                              size_t ws_size, hipStream_t stream) {
  const void* x_enc = d_in[0];
  const void* maskp = d_in[1];
  const void* We = d_in[2];  const void* be_ = d_in[3];
  const void* Wq = d_in[4];  const void* bq = d_in[5];
  const void* Wk = d_in[6];  const void* bk = d_in[7];
  const void* Wv = d_in[8];  const void* bv = d_in[9];
  const void* Wo = d_in[10]; const void* bo_ = d_in[11];
  const void* W1 = d_in[12]; const void* b1 = d_in[13];
  const void* W2 = d_in[14]; const void* b2 = d_in[15];
  const void* g1 = d_in[16]; const void* be1 = d_in[17];
  const void* g2 = d_in[18]; const void* be2 = d_in[19];
  const void* gf = d_in[20]; const void* bff = d_in[21];
  const void* Wp = d_in[22]; const void* bp = d_in[23];

  constexpr size_t MB = 1u << 20;
  char* w = (char*)d_ws;
  int*   mask_i  = (int*)w;                        // 32 KB
  int*   flags   = (int*)(w + 32768);
  float* scal    = (float*)(w + 32896);
  float* means   = (float*)(w + 33024);
  float* stdev   = (float*)(w + 33600);
  float* biasf   = (float*)(w + 36864);            // 73728 B -> ends 110592
  float* lnw     = (float*)(w + 114688);           // 4160 B
  float* patches = (float*)(w + 131072);           // 512 KB -> ends 655360
  unsigned short* WpT = (unsigned short*)(w + 655360);    // 16 KB
  unsigned short* qkvT = (unsigned short*)(w + 1 * MB);   // 6 MB
  unsigned short* WoT  = (unsigned short*)(w + 7 * MB);   // 2 MB
  unsigned short* W1T  = (unsigned short*)(w + 9 * MB);   // 8 MB
  unsigned short* W2T  = (unsigned short*)(w + 17 * MB);  // 8 MB
  unsigned short* tok  = (unsigned short*)(w + 25 * MB);  // 8 MB
  unsigned short* tmp  = (unsigned short*)(w + 33 * MB);  // 8 MB
  unsigned short* ob   = (unsigned short*)(w + 41 * MB);  // 8 MB
  unsigned short* qkv  = (unsigned short*)(w + 49 * MB);  // 24 MB -> ends 73
  unsigned short* vTb  = (unsigned short*)(w + 73 * MB);  // 8 MB -> ends 81
  unsigned short* hidden = ob;   // 32 MB alias over ob+qkv (dead by FFN1)

  k_setup<<<1, 256, 0, stream>>>(gf, maskp, mask_i, flags, scal);
  k_prep<<<141, 256, 0, stream>>>(x_enc, bq, bk, bv, bo_, b1, b2, gf, bff, Wp,
                                  bp, flags, means, stdev, biasf, lnw, WpT);
  k_transpose_all<<<12288, 256, 0, stream>>>(Wq, Wk, Wv, Wo, W1, W2, qkvT, WoT,
                                             W1T, W2T, flags);
  k_embed<<<M, 128, 0, stream>>>(x_enc, We, be_, flags, mask_i, means, stdev,
                                 patches, tok);
  for (int l = 0; l < 4; l++) {
    k_gemm<128, 128, 64><<<768, 256, 0, stream>>>(
        tok, qkvT + (size_t)l * 786432, biasf + l * 1536, nullptr, qkv, 1536,
        512, 0, 12);
    k_vtrans<<<dim3(32, 8, 4), 256, 0, stream>>>(qkv, vTb);
    k_attn<<<2048, 256, 0, stream>>>(qkv, vTb, ob);
    k_gemm<128, 64, 32><<<512, 256, 0, stream>>>(
        ob, WoT + (size_t)l * 262144, biasf + 6144 + l * 512, tok, tmp, 512,
        512, 0, 8);
    k_ln<<<M / 4, 256, 0, stream>>>(tmp, g1, be1, tok, flags, l * 512);
    k_gemm<128, 128, 64><<<1024, 256, 0, stream>>>(
        tok, W1T + (size_t)l * 1048576, biasf + 8192 + l * 2048, nullptr,
        hidden, 2048, 512, 1, 16);
    k_gemm<128, 64, 32><<<512, 256, 0, stream>>>(
        hidden, W2T + (size_t)l * 1048576, biasf + 16384 + l * 512, tok, tmp,
        512, 2048, 0, 8);
    k_ln<<<M / 4, 256, 0, stream>>>(tmp, g2, be2, tok, flags, l * 512);
  }
  k_lnloss<<<Bn * P, 128, 0, stream>>>(tok, lnw, WpT, patches, stdev, mask_i,
                                       scal);
  k_final<<<1, 1, 0, stream>>>(scal, flags, (unsigned*)d_out);
}

// Round 9
// 996.231 us; speedup vs baseline: 1.2225x; 1.0937x over previous
//
#include <hip/hip_runtime.h>
#include <hip/hip_bf16.h>

#define DEV __device__ __forceinline__

namespace {

constexpr int Bn  = 4, SEQ = 1024, NV = 32, PL = 16, D = 512, H = 8, DFF = 2048;
constexpr int P   = SEQ / PL;    // 64 patches
constexpr int L   = P * NV;      // 2048 tokens per batch
constexpr int M   = Bn * L;      // 8192 total token rows
constexpr int WIN = 4;

using short8   = __attribute__((ext_vector_type(8))) short;
using ushort8  = __attribute__((ext_vector_type(8))) unsigned short;
using float4v  = __attribute__((ext_vector_type(4))) float;

DEV float b2f(unsigned short u) { return __uint_as_float(((unsigned)u) << 16); }
DEV unsigned short f2b(float f) {
  unsigned fb = __float_as_uint(f);
  return (unsigned short)((fb + 0x7FFFu + ((fb >> 16) & 1u)) >> 16);
}
// flag-dispatched float load from an input tensor: bf=1 -> bf16, 0 -> fp32
DEV float ldf(const void* p, size_t idx, int bf) {
  if (bf) return b2f(((const unsigned short*)p)[idx]);
  return ((const float*)p)[idx];
}
// async global->LDS 16B: lds dest = wave-uniform base + lane*16
DEV void gll16(const void* gp, void* lp) {
  __builtin_amdgcn_global_load_lds(
      (const __attribute__((address_space(1))) void*)gp,
      (__attribute__((address_space(3))) void*)lp, 16, 0, 0);
}

// ---------------------------------------------------------------------------
// k_setup: detect float dtype + mask format, canonicalize mask, count masked.
// ---------------------------------------------------------------------------
__global__ void k_setup(const void* gf, const void* mask_raw, int* mask_i,
                        int* flags, float* scal) {
  __shared__ int s_gt1, s_oth, s_cnt;
  int tid = threadIdx.x;
  if (tid == 0) { s_gt1 = 0; s_oth = 0; s_cnt = 0; }
  __syncthreads();
  const unsigned* mw = (const unsigned*)mask_raw;
  int gt1 = 0, oth = 0;
  for (int i = tid; i < 2048; i += 256) {
    unsigned w = mw[i];
    if (w > 1u) { gt1 = 1; if (w != 0x3F800000u) oth = 1; }
  }
  if (gt1) atomicOr(&s_gt1, 1);
  if (oth) atomicOr(&s_oth, 1);
  __syncthreads();
  int fmt = (!s_gt1) ? 0 : (!s_oth ? 1 : 2);  // 0=int32, 1=f32, 2=bytes
  int cnt = 0;
  for (int i = tid; i < Bn * P * NV; i += 256) {
    int m;
    if (fmt == 0)      m = ((const int*)mask_raw)[i] != 0;
    else if (fmt == 1) m = ((const float*)mask_raw)[i] != 0.0f;
    else               m = ((const unsigned char*)mask_raw)[i] != 0;
    mask_i[i] = m; cnt += m;
  }
  atomicAdd(&s_cnt, cnt);
  __syncthreads();
  if (tid == 0) {
    unsigned w = *(const unsigned*)gf;
    flags[0] = ((w & 0xFFFFu) == 0x3F80u) ? 1 : 0;
    flags[1] = s_cnt;
    scal[0] = 0.f;
  }
}

// ---------------------------------------------------------------------------
// k_prep: blocks 0..31 -> per-(b,v) stats; blocks 32.. -> gather biases,
// final-LN weights (fp32), b_proj (fp32), and WpT (bf16 [t][d]).
// ---------------------------------------------------------------------------
__global__ void k_prep(const void* x, const void* bq, const void* bk,
                       const void* bv, const void* bo, const void* b1,
                       const void* b2, const void* gf, const void* bff,
                       const void* Wp, const void* bp, const int* flags,
                       float* means, float* stdev, float* biasf, float* lnw,
                       unsigned short* WpT) {
  int bf = flags[0];
  int tid = threadIdx.x;
  if (blockIdx.x < 32) {
    int bv_ = blockIdx.x * 4 + (tid >> 6);
    int b = bv_ >> 5, v = bv_ & 31;
    int lane = tid & 63;
    float s = 0.f, s2 = 0.f;
    for (int t = lane; t < SEQ; t += 64) {
      float val = ldf(x, (size_t)b * SEQ * NV + (size_t)t * NV + v, bf);
      s += val; s2 += val * val;
    }
    for (int off = 32; off; off >>= 1) {
      s += __shfl_xor(s, off); s2 += __shfl_xor(s2, off);
    }
    if (lane == 0) {
      float m = s / (float)SEQ;
      means[bv_] = m;
      stdev[bv_] = sqrtf(s2 / (float)SEQ - m * m + 1e-5f);
    }
    return;
  }
  int i = (blockIdx.x - 32) * 256 + tid;
  if (i < 18432) {
    int l = i / 4608, r = i % 4608;
    if (r < 1536) {
      float v = (r < 512) ? ldf(bq, l * 512 + r, bf)
              : (r < 1024) ? ldf(bk, l * 512 + r - 512, bf)
                           : ldf(bv, l * 512 + r - 1024, bf);
      biasf[l * 1536 + r] = v;
    } else if (r < 2048) {
      biasf[6144 + l * 512 + (r - 1536)] = ldf(bo, l * 512 + r - 1536, bf);
    } else if (r < 4096) {
      biasf[8192 + l * 2048 + (r - 2048)] = ldf(b1, l * 2048 + r - 2048, bf);
    } else {
      biasf[16384 + l * 512 + (r - 4096)] = ldf(b2, l * 512 + r - 4096, bf);
    }
  } else if (i < 19456) {
    int j = i - 18432;
    lnw[j] = (j < 512) ? ldf(gf, j, bf) : ldf(bff, j - 512, bf);
  } else if (i < 19472) {
    lnw[1024 + (i - 19456)] = ldf(bp, i - 19456, bf);
  } else if (i < 27664) {
    int j = i - 19472; int t = j >> 9, d = j & 511;
    WpT[j] = f2b(ldf(Wp, d * 16 + t, bf));
  }
}

// ---------------------------------------------------------------------------
// k_transpose_all: all 6 weight transposes in one dispatch.
// dst[l][n][k] (bf16) = src[l][k][n]. 32x32 LDS tile per block.
// ---------------------------------------------------------------------------
__global__ void k_transpose_all(const void* Wq, const void* Wk, const void* Wv,
                                const void* Wo, const void* W1, const void* W2,
                                unsigned short* qkvT, unsigned short* WoT,
                                unsigned short* W1T, unsigned short* W2T,
                                const int* flags) {
  int bf = flags[0];
  int id = blockIdx.x;
  const void* src; unsigned short* dst;
  int Kd, Nd, l, n0, k0, dstOff = 0;
  size_t srcLS, dstLS;
  if (id < 4096) {
    int tensor = id >> 10, rem = id & 1023;
    l = rem >> 8; int t = rem & 255;
    n0 = (t & 15) * 32; k0 = (t >> 4) * 32;
    Kd = 512; Nd = 512; srcLS = 262144;
    if (tensor == 0)      { src = Wq; dst = qkvT; dstLS = 786432; dstOff = 0; }
    else if (tensor == 1) { src = Wk; dst = qkvT; dstLS = 786432; dstOff = 262144; }
    else if (tensor == 2) { src = Wv; dst = qkvT; dstLS = 786432; dstOff = 524288; }
    else                  { src = Wo; dst = WoT;  dstLS = 262144; }
  } else if (id < 8192) {
    int rem = id - 4096; l = rem >> 10; int t = rem & 1023;
    n0 = (t & 63) * 32; k0 = (t >> 6) * 32;
    Kd = 512; Nd = 2048; srcLS = 1048576; src = W1; dst = W1T; dstLS = 1048576;
  } else {
    int rem = id - 8192; l = rem >> 10; int t = rem & 1023;
    n0 = (t & 15) * 32; k0 = (t >> 4) * 32;
    Kd = 2048; Nd = 512; srcLS = 1048576; src = W2; dst = W2T; dstLS = 1048576;
  }
  int tx = threadIdx.x & 31, ty = threadIdx.x >> 5;
  __shared__ float tile[32][33];
  for (int rr = ty; rr < 32; rr += 8)
    tile[rr][tx] =
        ldf(src, (size_t)l * srcLS + (size_t)(k0 + rr) * Nd + n0 + tx, bf);
  __syncthreads();
  for (int rr = ty; rr < 32; rr += 8)
    dst[(size_t)l * dstLS + dstOff + (size_t)(n0 + rr) * Kd + k0 + tx] =
        f2b(tile[tx][rr]);
}

// ---------------------------------------------------------------------------
// k_embed: patchify + instance-normalize, write patches (fp32) and embedded
// tokens (bf16), zeroing masked tokens. One block (128 thr) per token.
// ---------------------------------------------------------------------------
__global__ void k_embed(const void* x, const void* We, const void* be,
                        const int* flags, const int* mask_i,
                        const float* means, const float* stdev,
                        float* patches, unsigned short* tok) {
  int idx = blockIdx.x;
  int b = idx >> 11, pv = idx & 2047, p = pv >> 5, v = pv & 31;
  int bf = flags[0];
  __shared__ float pvs[PL];
  int tid = threadIdx.x;
  float m = means[b * NV + v], sd = stdev[b * NV + v];
  if (tid < PL) {
    float val =
        (ldf(x, (size_t)b * SEQ * NV + (size_t)(p * PL + tid) * NV + v, bf) -
         m) / sd;
    pvs[tid] = val;
    patches[(size_t)idx * PL + tid] = val;
  }
  __syncthreads();
  int masked = mask_i[idx];
  for (int d = tid; d < D; d += 128) {
    float acc = ldf(be, d, bf);
    for (int t = 0; t < PL; t++) acc += pvs[t] * ldf(We, t * D + d, bf);
    tok[(size_t)idx * D + d] = masked ? f2b(0.f) : f2b(acc);
  }
}

// ---------------------------------------------------------------------------
// k_gemm<BM,BN,WN>: C = act(A @ W^T' + bias [+resid]) in bf16. BK=64.
// Linear grid, XCD-swizzled. Epilogue goes through LDS (reusing As/Bs) for
// fully-coalesced ushort8 stores and vectorized resid loads. For the QKV
// GEMM (vTp != null), tiles with bn >= 1024 are the V projection: staged
// TRANSPOSED in LDS and written as vT[b][hd][token] with full-line stores.
// q/k tiles go to C with row stride cs (=1024 for QKV).
// ---------------------------------------------------------------------------
template <int BM, int BN, int WN>
__global__ __launch_bounds__(256) void k_gemm(
    const unsigned short* __restrict__ A, const unsigned short* __restrict__ W,
    const float* __restrict__ bias, const unsigned short* __restrict__ resid,
    unsigned short* __restrict__ C, unsigned short* __restrict__ vTp, int cs,
    int Kk, int act, int nbn) {
  constexpr int FI = 4, FJ = WN / 16, NWN = BN / WN;
  __shared__ __align__(16) char sm[BM * 128 + BN * 128];
  char* As = sm;
  char* Bs = sm + BM * 128;
  unsigned short* Cl = (unsigned short*)sm;
  int tid = threadIdx.x, lane = tid & 63, w = tid >> 6;
  int lane15 = lane & 15, q = lane >> 4;
  int wm = w / NWN, wn = w % NWN;
  int id = blockIdx.x;
  int xcd = id & 7, loc = id >> 3;
  int bn = (loc % nbn) * BN;
  int bm = (xcd * ((int)(gridDim.x >> 3) / nbn) + loc / nbn) * BM;
  int lrow = lane >> 3, lc = lane & 7;
  float4v acc[FI][FJ];
  for (int i = 0; i < FI; i++)
    for (int j = 0; j < FJ; j++) acc[i][j] = 0;
  for (int k0 = 0; k0 < Kk; k0 += 64) {
    if (k0) __syncthreads();
    for (int i = w; i < BM / 8; i += 4) {
      int row = i * 8 + lrow;
      gll16(A + (size_t)(bm + row) * Kk + k0 + ((lc ^ (row & 7)) << 3),
            As + i * 1024);
    }
    for (int i = w; i < BN / 8; i += 4) {
      int row = i * 8 + lrow;
      gll16(W + (size_t)(bn + row) * Kk + k0 + ((lc ^ (row & 7)) << 3),
            Bs + i * 1024);
    }
    __syncthreads();
    short8 a[2][FI], b[2][FJ];
    for (int h = 0; h < 2; h++) {
      for (int i = 0; i < FI; i++) {
        int rr = wm * 64 + i * 16 + lane15;
        a[h][i] =
            *(const short8*)(As + rr * 128 + (((h * 4 + q) ^ (rr & 7)) << 4));
      }
      for (int j = 0; j < FJ; j++) {
        int rr = wn * WN + j * 16 + lane15;
        b[h][j] =
            *(const short8*)(Bs + rr * 128 + (((h * 4 + q) ^ (rr & 7)) << 4));
      }
    }
    for (int h = 0; h < 2; h++)
      for (int i = 0; i < FI; i++)
        for (int j = 0; j < FJ; j++)
          acc[i][j] = __builtin_amdgcn_mfma_f32_16x16x32_bf16(
              a[h][i], b[h][j], acc[i][j], 0, 0, 0);
  }
  // ---- epilogue through LDS ----
  int vmode = (vTp != nullptr) && (bn >= 1024);
  __syncthreads();  // all MFMAs done reading As/Bs
  for (int i = 0; i < FI; i++) {
    for (int j = 0; j < FJ; j++) {
      int col = wn * WN + j * 16 + lane15;        // tile-local col
      float bv = bias[bn + col];
      for (int r = 0; r < 4; r++) {
        int row = wm * 64 + i * 16 + q * 4 + r;   // tile-local row
        float cv = acc[i][j][r] + bv;
        if (act) cv = 0.5f * cv * (1.f + erff(cv * 0.70710678f));
        if (!vmode)
          Cl[row * BN + (((col >> 3) ^ (row & 7)) << 3) + (col & 7)] = f2b(cv);
        else
          Cl[col * BM + (((row >> 3) ^ (col & 7)) << 3) + (row & 7)] = f2b(cv);
      }
    }
  }
  __syncthreads();
  if (!vmode) {
    constexpr int TOT = BM * BN / 8;
    for (int e = tid; e < TOT; e += 256) {
      int rr = e / (BN / 8), c8 = e % (BN / 8);
      ushort8 u = *(const ushort8*)(Cl + rr * BN + ((c8 ^ (rr & 7)) << 3));
      size_t off = (size_t)(bm + rr) * cs + bn + c8 * 8;
      if (resid) {
        ushort8 rv = *(const ushort8*)(resid + off);
        for (int t = 0; t < 8; t++) u[t] = f2b(b2f(u[t]) + b2f(rv[t]));
      }
      *(ushort8*)(C + off) = u;
    }
  } else {
    constexpr int TOT = BM * BN / 8;
    for (int e = tid; e < TOT; e += 256) {
      int cc = e / (BM / 8), t8 = e % (BM / 8);
      ushort8 u = *(const ushort8*)(Cl + cc * BM + ((t8 ^ (cc & 7)) << 3));
      int hd = bn - 1024 + cc;
      int rowg = bm + t8 * 8;
      int bb = rowg >> 11, tokin = rowg & 2047;
      *(ushort8*)(vTp + ((size_t)(bb * 512 + hd)) * 2048 + tokin) = u;
    }
  }
}

// ---------------------------------------------------------------------------
// k_attn: banded MFMA attention, fragment-direct global loads with 1-deep
// register prefetch (R6 occupancy profile: 19.5 KB LDS, VGPR well under 64
// -> 8 blocks/CU. Do NOT stage K in LDS (R7: 56 KB -> 2 blocks/CU, 62->100us).
// qk: [M][1024] bf16 (q|k). vT: [b*512+hd][2048]. o: [M][512].
// Softmax: no max-subtraction (|scores| <~ 5, exp shift-invariant), b128 IO.
// ---------------------------------------------------------------------------
__global__ __launch_bounds__(256) void k_attn(
    const unsigned short* __restrict__ qk,
    const unsigned short* __restrict__ vT, unsigned short* __restrict__ o) {
  constexpr int SSTR = 304;
  __shared__ __align__(16) unsigned short S[32 * SSTR];
  int id = blockIdx.x;
  int xcd = id & 7, rr_ = id >> 3;
  int p = xcd * 8 + (rr_ & 7);
  int h = (rr_ >> 3) & 7;
  int b = rr_ >> 6;
  int tid = threadIdx.x, lane = tid & 63, w = tid >> 6;
  int lane15 = lane & 15, q = lane >> 4;
  int p0 = max(0, p - WIN), p1 = min(P - 1, p + WIN);
  int nk = (p1 - p0 + 1) * 32;     // multiple of 32, in [160,288]
  int ntiles = nk >> 4;
  size_t base = (size_t)b * L;
  int mtile = w & 1;
  // Q fragments (A-operand), direct global
  const unsigned short* qrow =
      qk + (base + p * 32 + mtile * 16 + lane15) * 1024 + h * 64 + q * 8;
  short8 aq0 = *(const short8*)(qrow);
  short8 aq1 = *(const short8*)(qrow + 32);
  // phase A: S = (Q K^T) * scale, bf16 into LDS, 1-deep K prefetch
  const unsigned short* kbase =
      qk + (base + p0 * 32) * 1024 + 512 + h * 64 + q * 8;
  {
    int nt = w >> 1;
    const unsigned short* kr = kbase + (size_t)(nt * 16 + lane15) * 1024;
    short8 kc0 = *(const short8*)(kr);
    short8 kc1 = *(const short8*)(kr + 32);
    for (; nt < ntiles; nt += 2) {
      short8 kn0, kn1;
      if (nt + 2 < ntiles) {
        const unsigned short* kr2 =
            kbase + (size_t)((nt + 2) * 16 + lane15) * 1024;
        kn0 = *(const short8*)(kr2);
        kn1 = *(const short8*)(kr2 + 32);
      }
      float4v s4 = 0;
      s4 = __builtin_amdgcn_mfma_f32_16x16x32_bf16(aq0, kc0, s4, 0, 0, 0);
      s4 = __builtin_amdgcn_mfma_f32_16x16x32_bf16(aq1, kc1, s4, 0, 0, 0);
      for (int r = 0; r < 4; r++)
        S[(mtile * 16 + q * 4 + r) * SSTR + nt * 16 + lane15] =
            f2b(s4[r] * 0.125f);
      kc0 = kn0; kc1 = kn1;
    }
  }
  __syncthreads();
  // phase B: softmax without max-sub, b128 LDS IO, exp kept packed bf16
  {
    int row = tid >> 3, c = tid & 7;
    ushort8 eb[5];
    float sum = 0.f;
    for (int k = 0; k < 5; k++) {
      int j0 = c * 8 + k * 64;
      if (j0 < nk) {
        ushort8 u = *(const ushort8*)(S + row * SSTR + j0);
        ushort8 e8;
        for (int t = 0; t < 8; t++) {
          float e = __expf(b2f(u[t]));
          sum += e;
          e8[t] = f2b(e);
        }
        eb[k] = e8;
      }
    }
    for (int off = 1; off < 8; off <<= 1) sum += __shfl_xor(sum, off);
    float inv = 1.f / sum;
    for (int k = 0; k < 5; k++) {
      int j0 = c * 8 + k * 64;
      if (j0 < nk) {
        ushort8 e8 = eb[k], u;
        for (int t = 0; t < 8; t++) u[t] = f2b(b2f(e8[t]) * inv);
        *(ushort8*)(S + row * SSTR + j0) = u;
      }
    }
  }
  __syncthreads();
  // phase C: O = P V, V fragment-direct from vT with 1-deep prefetch
  int ntb = (w >> 1) * 2;
  int nkt = nk >> 5;
  const unsigned short* vb0 =
      vT + (size_t)(b * 512 + h * 64 + ntb * 16 + lane15) * 2048 + p0 * 32 +
      q * 8;
  const unsigned short* vb1 = vb0 + 16 * 2048;
  const unsigned short* prow = S + (mtile * 16 + lane15) * SSTR + q * 8;
  float4v oa0 = 0, oa1 = 0;
  short8 ap = *(const short8*)(prow);
  short8 v0 = *(const short8*)(vb0);
  short8 v1 = *(const short8*)(vb1);
  for (int kt = 0; kt < nkt; kt++) {
    short8 apN, v0N, v1N;
    if (kt + 1 < nkt) {
      apN = *(const short8*)(prow + (kt + 1) * 32);
      v0N = *(const short8*)(vb0 + (kt + 1) * 32);
      v1N = *(const short8*)(vb1 + (kt + 1) * 32);
    }
    oa0 = __builtin_amdgcn_mfma_f32_16x16x32_bf16(ap, v0, oa0, 0, 0, 0);
    oa1 = __builtin_amdgcn_mfma_f32_16x16x32_bf16(ap, v1, oa1, 0, 0, 0);
    ap = apN; v0 = v0N; v1 = v1N;
  }
  // stage O in LDS (reuse S), then store full 128B lines cooperatively
  __syncthreads();
  for (int r = 0; r < 4; r++) {
    S[(mtile * 16 + q * 4 + r) * 72 + ntb * 16 + lane15] = f2b(oa0[r]);
    S[(mtile * 16 + q * 4 + r) * 72 + (ntb + 1) * 16 + lane15] = f2b(oa1[r]);
  }
  __syncthreads();
  {
    int row = tid >> 3, c8 = tid & 7;
    ushort8 val = *(const ushort8*)(S + row * 72 + c8 * 8);
    *(ushort8*)(o + (base + p * 32 + row) * 512 + h * 64 + c8 * 8) = val;
  }
}

// ---------------------------------------------------------------------------
// k_ln: layernorm over D=512 per token, bf16 in/out. 4 rows per block.
// ---------------------------------------------------------------------------
__global__ void k_ln(const unsigned short* __restrict__ x, const void* g,
                     const void* bta, unsigned short* __restrict__ out,
                     const int* flags, int goff) {
  int bf = flags[0];
  int row = blockIdx.x * 4 + (threadIdx.x >> 6);
  int lane = threadIdx.x & 63;
  ushort8 u = *(const ushort8*)(x + (size_t)row * D + lane * 8);
  float v[8]; float s = 0.f, s2 = 0.f;
  for (int t = 0; t < 8; t++) {
    v[t] = b2f(u[t]); s += v[t]; s2 += v[t] * v[t];
  }
  for (int off = 32; off; off >>= 1) {
    s += __shfl_xor(s, off); s2 += __shfl_xor(s2, off);
  }
  float m = s / (float)D;
  float inv = rsqrtf(s2 / (float)D - m * m + 1e-5f);
  ushort8 ou;
  for (int t = 0; t < 8; t++) {
    int c = lane * 8 + t;
    ou[t] = f2b((v[t] - m) * inv * ldf(g, goff + c, bf) + ldf(bta, goff + c, bf));
  }
  *(ushort8*)(out + (size_t)row * D + lane * 8) = ou;
}

// ---------------------------------------------------------------------------
// k_lnloss: fused final LN + recon head (MFMA) + masked MSE.
// ---------------------------------------------------------------------------
__global__ __launch_bounds__(128) void k_lnloss(
    const unsigned short* __restrict__ tok, const float* __restrict__ lnw,
    const unsigned short* __restrict__ WpT, const float* __restrict__ patches,
    const float* __restrict__ stdev, const int* __restrict__ mask_i,
    float* scal) {
  constexpr int RS = 520;  // padded LDS row stride (elements)
  __shared__ __align__(16) unsigned short As[32 * RS];
  __shared__ __align__(16) unsigned short Bs[16 * RS];
  int bpI = blockIdx.x; int b = bpI >> 6, p = bpI & 63;
  int tid = threadIdx.x;
  int row = tid >> 2, cg = tid & 3;   // 4 threads per token row
  size_t tokbase = (size_t)(b * L + p * 32);
  float s = 0.f, s2 = 0.f;
  for (int i = 0; i < 16; i++) {
    int c = cg + i * 4;
    ushort8 u = *(const ushort8*)(tok + (tokbase + row) * D + c * 8);
    for (int t = 0; t < 8; t++) { float v = b2f(u[t]); s += v; s2 += v * v; }
  }
  s += __shfl_xor(s, 1); s += __shfl_xor(s, 2);
  s2 += __shfl_xor(s2, 1); s2 += __shfl_xor(s2, 2);
  float m = s / (float)D;
  float inv = rsqrtf(s2 / (float)D - m * m + 1e-5f);
  for (int i = 0; i < 16; i++) {
    int c = cg + i * 4;
    ushort8 u = *(const ushort8*)(tok + (tokbase + row) * D + c * 8);
    ushort8 o;
    for (int t = 0; t < 8; t++) {
      int col = c * 8 + t;
      o[t] = f2b((b2f(u[t]) - m) * inv * lnw[col] + lnw[512 + col]);
    }
    *(ushort8*)(As + row * RS + c * 8) = o;
  }
  for (int e = tid; e < 16 * 64; e += 128) {
    int r = e >> 6, c = e & 63;
    *(ushort8*)(Bs + r * RS + c * 8) = *(const ushort8*)(WpT + r * 512 + c * 8);
  }
  __syncthreads();
  int w = tid >> 6, lane = tid & 63, lane15 = lane & 15, q = lane >> 4;
  float4v acc = 0;
  for (int kt = 0; kt < 16; kt++) {
    short8 a = *(const short8*)(As + (w * 16 + lane15) * RS + kt * 32 + q * 8);
    short8 bfr = *(const short8*)(Bs + lane15 * RS + kt * 32 + q * 8);
    acc = __builtin_amdgcn_mfma_f32_16x16x32_bf16(a, bfr, acc, 0, 0, 0);
  }
  float local = 0.f;
  int t = lane15;
  for (int r = 0; r < 4; r++) {
    int v = w * 16 + q * 4 + r;
    int tokidx = b * 2048 + p * 32 + v;
    if (mask_i[tokidx]) {
      float recon = acc[r] + lnw[1024 + t];
      float diff = recon - patches[(size_t)tokidx * 16 + t];
      float sc = stdev[b * 32 + v];
      local += sc * sc * diff * diff;
    }
  }
  for (int off = 32; off; off >>= 1) local += __shfl_xor(local, off);
  if (lane == 0) atomicAdd(&scal[0], local);
}

__global__ void k_final(const float* scal, const int* flags, unsigned* out) {
  float denom = (float)flags[1] * (float)PL;
  if (denom == 0.f) denom = 1.f;
  float loss = scal[0] / denom;
  unsigned fb = __float_as_uint(loss);
  unsigned u = (fb + 0x7FFFu + ((fb >> 16) & 1u)) >> 16;
  out[0] = (u << 16) | u;
}

}  // namespace

extern "C" void kernel_launch(void* const* d_in, const int* in_sizes, int n_in,
                              void* d_out, int out_size, void* d_ws,
                              size_t ws_size, hipStream_t stream) {
  const void* x_enc = d_in[0];
  const void* maskp = d_in[1];
  const void* We = d_in[2];  const void* be_ = d_in[3];
  const void* Wq = d_in[4];  const void* bq = d_in[5];
  const void* Wk = d_in[6];  const void* bk = d_in[7];
  const void* Wv = d_in[8];  const void* bv = d_in[9];
  const void* Wo = d_in[10]; const void* bo_ = d_in[11];
  const void* W1 = d_in[12]; const void* b1 = d_in[13];
  const void* W2 = d_in[14]; const void* b2 = d_in[15];
  const void* g1 = d_in[16]; const void* be1 = d_in[17];
  const void* g2 = d_in[18]; const void* be2 = d_in[19];
  const void* gf = d_in[20]; const void* bff = d_in[21];
  const void* Wp = d_in[22]; const void* bp = d_in[23];

  constexpr size_t MB = 1u << 20;
  char* w = (char*)d_ws;
  int*   mask_i  = (int*)w;                        // 32 KB
  int*   flags   = (int*)(w + 32768);
  float* scal    = (float*)(w + 32896);
  float* means   = (float*)(w + 33024);
  float* stdev   = (float*)(w + 33600);
  float* biasf   = (float*)(w + 36864);            // 73728 B -> ends 110592
  float* lnw     = (float*)(w + 114688);           // 4160 B
  float* patches = (float*)(w + 131072);           // 512 KB -> ends 655360
  unsigned short* WpT = (unsigned short*)(w + 655360);    // 16 KB
  unsigned short* qkvT = (unsigned short*)(w + 1 * MB);   // 6 MB
  unsigned short* WoT  = (unsigned short*)(w + 7 * MB);   // 2 MB
  unsigned short* W1T  = (unsigned short*)(w + 9 * MB);   // 8 MB
  unsigned short* W2T  = (unsigned short*)(w + 17 * MB);  // 8 MB
  unsigned short* tok  = (unsigned short*)(w + 25 * MB);  // 8 MB
  unsigned short* tmp  = (unsigned short*)(w + 33 * MB);  // 8 MB
  unsigned short* ob   = (unsigned short*)(w + 41 * MB);  // 8 MB
  unsigned short* qk   = (unsigned short*)(w + 49 * MB);  // 16 MB -> ends 65
  unsigned short* vTb  = (unsigned short*)(w + 73 * MB);  // 8 MB -> ends 81
  unsigned short* hidden = ob;   // 32 MB alias over ob+qk (dead by FFN1)

  k_setup<<<1, 256, 0, stream>>>(gf, maskp, mask_i, flags, scal);
  k_prep<<<141, 256, 0, stream>>>(x_enc, bq, bk, bv, bo_, b1, b2, gf, bff, Wp,
                                  bp, flags, means, stdev, biasf, lnw, WpT);
  k_transpose_all<<<12288, 256, 0, stream>>>(Wq, Wk, Wv, Wo, W1, W2, qkvT, WoT,
                                             W1T, W2T, flags);
  k_embed<<<M, 128, 0, stream>>>(x_enc, We, be_, flags, mask_i, means, stdev,
                                 patches, tok);
  for (int l = 0; l < 4; l++) {
    k_gemm<128, 128, 64><<<768, 256, 0, stream>>>(
        tok, qkvT + (size_t)l * 786432, biasf + l * 1536, nullptr, qk, vTb,
        1024, 512, 0, 12);
    k_attn<<<2048, 256, 0, stream>>>(qk, vTb, ob);
    k_gemm<128, 64, 32><<<512, 256, 0, stream>>>(
        ob, WoT + (size_t)l * 262144, biasf + 6144 + l * 512, tok, tmp,
        nullptr, 512, 512, 0, 8);
    k_ln<<<M / 4, 256, 0, stream>>>(tmp, g1, be1, tok, flags, l * 512);
    k_gemm<128, 128, 64><<<1024, 256, 0, stream>>>(
        tok, W1T + (size_t)l * 1048576, biasf + 8192 + l * 2048, nullptr,
        hidden, nullptr, 2048, 512, 1, 16);
    k_gemm<128, 64, 32><<<512, 256, 0, stream>>>(
        hidden, W2T + (size_t)l * 1048576, biasf + 16384 + l * 512, tok, tmp,
        nullptr, 512, 2048, 0, 8);
    k_ln<<<M / 4, 256, 0, stream>>>(tmp, g2, be2, tok, flags, l * 512);
  }
  k_lnloss<<<Bn * P, 128, 0, stream>>>(tok, lnw, WpT, patches, stdev, mask_i,
                                       scal);
  k_final<<<1, 1, 0, stream>>>(scal, flags, (unsigned*)d_out);
}

// Round 10
// 923.543 us; speedup vs baseline: 1.3187x; 1.0787x over previous
//
#include <hip/hip_runtime.h>
#include <hip/hip_bf16.h>

#define DEV __device__ __forceinline__

namespace {

constexpr int Bn  = 4, SEQ = 1024, NV = 32, PL = 16, D = 512, H = 8, DFF = 2048;
constexpr int P   = SEQ / PL;    // 64 patches
constexpr int L   = P * NV;      // 2048 tokens per batch
constexpr int M   = Bn * L;      // 8192 total token rows
constexpr int WIN = 4;

using short8   = __attribute__((ext_vector_type(8))) short;
using ushort8  = __attribute__((ext_vector_type(8))) unsigned short;
using float4v  = __attribute__((ext_vector_type(4))) float;

DEV float b2f(unsigned short u) { return __uint_as_float(((unsigned)u) << 16); }
DEV unsigned short f2b(float f) {
  unsigned fb = __float_as_uint(f);
  return (unsigned short)((fb + 0x7FFFu + ((fb >> 16) & 1u)) >> 16);
}
// flag-dispatched float load from an input tensor: bf=1 -> bf16, 0 -> fp32
DEV float ldf(const void* p, size_t idx, int bf) {
  if (bf) return b2f(((const unsigned short*)p)[idx]);
  return ((const float*)p)[idx];
}
// async global->LDS 16B: lds dest = wave-uniform base + lane*16
DEV void gll16(const void* gp, void* lp) {
  __builtin_amdgcn_global_load_lds(
      (const __attribute__((address_space(1))) void*)gp,
      (__attribute__((address_space(3))) void*)lp, 16, 0, 0);
}

// ---------------------------------------------------------------------------
// k_setup: detect float dtype + mask format, canonicalize mask, count masked.
// ---------------------------------------------------------------------------
__global__ void k_setup(const void* gf, const void* mask_raw, int* mask_i,
                        int* flags, float* scal) {
  __shared__ int s_gt1, s_oth, s_cnt;
  int tid = threadIdx.x;
  if (tid == 0) { s_gt1 = 0; s_oth = 0; s_cnt = 0; }
  __syncthreads();
  const unsigned* mw = (const unsigned*)mask_raw;
  int gt1 = 0, oth = 0;
  for (int i = tid; i < 2048; i += 256) {
    unsigned w = mw[i];
    if (w > 1u) { gt1 = 1; if (w != 0x3F800000u) oth = 1; }
  }
  if (gt1) atomicOr(&s_gt1, 1);
  if (oth) atomicOr(&s_oth, 1);
  __syncthreads();
  int fmt = (!s_gt1) ? 0 : (!s_oth ? 1 : 2);  // 0=int32, 1=f32, 2=bytes
  int cnt = 0;
  for (int i = tid; i < Bn * P * NV; i += 256) {
    int m;
    if (fmt == 0)      m = ((const int*)mask_raw)[i] != 0;
    else if (fmt == 1) m = ((const float*)mask_raw)[i] != 0.0f;
    else               m = ((const unsigned char*)mask_raw)[i] != 0;
    mask_i[i] = m; cnt += m;
  }
  atomicAdd(&s_cnt, cnt);
  __syncthreads();
  if (tid == 0) {
    unsigned w = *(const unsigned*)gf;
    flags[0] = ((w & 0xFFFFu) == 0x3F80u) ? 1 : 0;
    flags[1] = s_cnt;
    scal[0] = 0.f;
  }
}

// ---------------------------------------------------------------------------
// k_prep: blocks 0..31 -> per-(b,v) stats; blocks 32.. -> gather biases,
// final-LN weights (fp32), b_proj (fp32), and WpT (bf16 [t][d]).
// ---------------------------------------------------------------------------
__global__ void k_prep(const void* x, const void* bq, const void* bk,
                       const void* bv, const void* bo, const void* b1,
                       const void* b2, const void* gf, const void* bff,
                       const void* Wp, const void* bp, const int* flags,
                       float* means, float* stdev, float* biasf, float* lnw,
                       unsigned short* WpT) {
  int bf = flags[0];
  int tid = threadIdx.x;
  if (blockIdx.x < 32) {
    int bv_ = blockIdx.x * 4 + (tid >> 6);
    int b = bv_ >> 5, v = bv_ & 31;
    int lane = tid & 63;
    float s = 0.f, s2 = 0.f;
    for (int t = lane; t < SEQ; t += 64) {
      float val = ldf(x, (size_t)b * SEQ * NV + (size_t)t * NV + v, bf);
      s += val; s2 += val * val;
    }
    for (int off = 32; off; off >>= 1) {
      s += __shfl_xor(s, off); s2 += __shfl_xor(s2, off);
    }
    if (lane == 0) {
      float m = s / (float)SEQ;
      means[bv_] = m;
      stdev[bv_] = sqrtf(s2 / (float)SEQ - m * m + 1e-5f);
    }
    return;
  }
  int i = (blockIdx.x - 32) * 256 + tid;
  if (i < 18432) {
    int l = i / 4608, r = i % 4608;
    if (r < 1536) {
      float v = (r < 512) ? ldf(bq, l * 512 + r, bf)
              : (r < 1024) ? ldf(bk, l * 512 + r - 512, bf)
                           : ldf(bv, l * 512 + r - 1024, bf);
      biasf[l * 1536 + r] = v;
    } else if (r < 2048) {
      biasf[6144 + l * 512 + (r - 1536)] = ldf(bo, l * 512 + r - 1536, bf);
    } else if (r < 4096) {
      biasf[8192 + l * 2048 + (r - 2048)] = ldf(b1, l * 2048 + r - 2048, bf);
    } else {
      biasf[16384 + l * 512 + (r - 4096)] = ldf(b2, l * 512 + r - 4096, bf);
    }
  } else if (i < 19456) {
    int j = i - 18432;
    lnw[j] = (j < 512) ? ldf(gf, j, bf) : ldf(bff, j - 512, bf);
  } else if (i < 19472) {
    lnw[1024 + (i - 19456)] = ldf(bp, i - 19456, bf);
  } else if (i < 27664) {
    int j = i - 19472; int t = j >> 9, d = j & 511;
    WpT[j] = f2b(ldf(Wp, d * 16 + t, bf));
  }
}

// ---------------------------------------------------------------------------
// k_transpose_all: all 6 weight transposes in one dispatch.
// dst[l][n][k] (bf16) = src[l][k][n]. 32x32 LDS tile per block.
// ---------------------------------------------------------------------------
__global__ void k_transpose_all(const void* Wq, const void* Wk, const void* Wv,
                                const void* Wo, const void* W1, const void* W2,
                                unsigned short* qkvT, unsigned short* WoT,
                                unsigned short* W1T, unsigned short* W2T,
                                const int* flags) {
  int bf = flags[0];
  int id = blockIdx.x;
  const void* src; unsigned short* dst;
  int Kd, Nd, l, n0, k0, dstOff = 0;
  size_t srcLS, dstLS;
  if (id < 4096) {
    int tensor = id >> 10, rem = id & 1023;
    l = rem >> 8; int t = rem & 255;
    n0 = (t & 15) * 32; k0 = (t >> 4) * 32;
    Kd = 512; Nd = 512; srcLS = 262144;
    if (tensor == 0)      { src = Wq; dst = qkvT; dstLS = 786432; dstOff = 0; }
    else if (tensor == 1) { src = Wk; dst = qkvT; dstLS = 786432; dstOff = 262144; }
    else if (tensor == 2) { src = Wv; dst = qkvT; dstLS = 786432; dstOff = 524288; }
    else                  { src = Wo; dst = WoT;  dstLS = 262144; }
  } else if (id < 8192) {
    int rem = id - 4096; l = rem >> 10; int t = rem & 1023;
    n0 = (t & 63) * 32; k0 = (t >> 6) * 32;
    Kd = 512; Nd = 2048; srcLS = 1048576; src = W1; dst = W1T; dstLS = 1048576;
  } else {
    int rem = id - 8192; l = rem >> 10; int t = rem & 1023;
    n0 = (t & 15) * 32; k0 = (t >> 4) * 32;
    Kd = 2048; Nd = 512; srcLS = 1048576; src = W2; dst = W2T; dstLS = 1048576;
  }
  int tx = threadIdx.x & 31, ty = threadIdx.x >> 5;
  __shared__ float tile[32][33];
  for (int rr = ty; rr < 32; rr += 8)
    tile[rr][tx] =
        ldf(src, (size_t)l * srcLS + (size_t)(k0 + rr) * Nd + n0 + tx, bf);
  __syncthreads();
  for (int rr = ty; rr < 32; rr += 8)
    dst[(size_t)l * dstLS + dstOff + (size_t)(n0 + rr) * Kd + k0 + tx] =
        f2b(tile[tx][rr]);
}

// ---------------------------------------------------------------------------
// k_embed: patchify + instance-normalize, write patches (fp32) and embedded
// tokens (bf16), zeroing masked tokens. One block (128 thr) per token.
// ---------------------------------------------------------------------------
__global__ void k_embed(const void* x, const void* We, const void* be,
                        const int* flags, const int* mask_i,
                        const float* means, const float* stdev,
                        float* patches, unsigned short* tok) {
  int idx = blockIdx.x;
  int b = idx >> 11, pv = idx & 2047, p = pv >> 5, v = pv & 31;
  int bf = flags[0];
  __shared__ float pvs[PL];
  int tid = threadIdx.x;
  float m = means[b * NV + v], sd = stdev[b * NV + v];
  if (tid < PL) {
    float val =
        (ldf(x, (size_t)b * SEQ * NV + (size_t)(p * PL + tid) * NV + v, bf) -
         m) / sd;
    pvs[tid] = val;
    patches[(size_t)idx * PL + tid] = val;
  }
  __syncthreads();
  int masked = mask_i[idx];
  for (int d = tid; d < D; d += 128) {
    float acc = ldf(be, d, bf);
    for (int t = 0; t < PL; t++) acc += pvs[t] * ldf(We, t * D + d, bf);
    tok[(size_t)idx * D + d] = masked ? f2b(0.f) : f2b(acc);
  }
}

// ---------------------------------------------------------------------------
// k_gemm<BM,BN,WN>: C = act(A @ W^T' + bias [+resid]) in bf16. BK=64.
// Linear grid, XCD-swizzled. Epilogue through LDS for coalesced ushort8 IO.
// vTp != null (QKV): bn >= 1024 tiles are V, staged transposed -> vT.
// R9: 128x128 tiles ran at 4 blocks/CU (grid-limited), MfmaUtil 13% --
// narrower tiles raise resident waves (latency-bound regime).
// ---------------------------------------------------------------------------
template <int BM, int BN, int WN>
__global__ __launch_bounds__(256) void k_gemm(
    const unsigned short* __restrict__ A, const unsigned short* __restrict__ W,
    const float* __restrict__ bias, const unsigned short* __restrict__ resid,
    unsigned short* __restrict__ C, unsigned short* __restrict__ vTp, int cs,
    int Kk, int act, int nbn) {
  constexpr int FI = 4, FJ = WN / 16, NWN = BN / WN;
  __shared__ __align__(16) char sm[BM * 128 + BN * 128];
  char* As = sm;
  char* Bs = sm + BM * 128;
  unsigned short* Cl = (unsigned short*)sm;
  int tid = threadIdx.x, lane = tid & 63, w = tid >> 6;
  int lane15 = lane & 15, q = lane >> 4;
  int wm = w / NWN, wn = w % NWN;
  int id = blockIdx.x;
  int xcd = id & 7, loc = id >> 3;
  int bn = (loc % nbn) * BN;
  int bm = (xcd * ((int)(gridDim.x >> 3) / nbn) + loc / nbn) * BM;
  int lrow = lane >> 3, lc = lane & 7;
  float4v acc[FI][FJ];
  for (int i = 0; i < FI; i++)
    for (int j = 0; j < FJ; j++) acc[i][j] = 0;
  for (int k0 = 0; k0 < Kk; k0 += 64) {
    if (k0) __syncthreads();
    for (int i = w; i < BM / 8; i += 4) {
      int row = i * 8 + lrow;
      gll16(A + (size_t)(bm + row) * Kk + k0 + ((lc ^ (row & 7)) << 3),
            As + i * 1024);
    }
    for (int i = w; i < BN / 8; i += 4) {
      int row = i * 8 + lrow;
      gll16(W + (size_t)(bn + row) * Kk + k0 + ((lc ^ (row & 7)) << 3),
            Bs + i * 1024);
    }
    __syncthreads();
    short8 a[2][FI], b[2][FJ];
    for (int h = 0; h < 2; h++) {
      for (int i = 0; i < FI; i++) {
        int rr = wm * 64 + i * 16 + lane15;
        a[h][i] =
            *(const short8*)(As + rr * 128 + (((h * 4 + q) ^ (rr & 7)) << 4));
      }
      for (int j = 0; j < FJ; j++) {
        int rr = wn * WN + j * 16 + lane15;
        b[h][j] =
            *(const short8*)(Bs + rr * 128 + (((h * 4 + q) ^ (rr & 7)) << 4));
      }
    }
    for (int h = 0; h < 2; h++)
      for (int i = 0; i < FI; i++)
        for (int j = 0; j < FJ; j++)
          acc[i][j] = __builtin_amdgcn_mfma_f32_16x16x32_bf16(
              a[h][i], b[h][j], acc[i][j], 0, 0, 0);
  }
  // ---- epilogue through LDS ----
  int vmode = (vTp != nullptr) && (bn >= 1024);
  __syncthreads();  // all MFMAs done reading As/Bs
  for (int i = 0; i < FI; i++) {
    for (int j = 0; j < FJ; j++) {
      int col = wn * WN + j * 16 + lane15;        // tile-local col
      float bv = bias[bn + col];
      for (int r = 0; r < 4; r++) {
        int row = wm * 64 + i * 16 + q * 4 + r;   // tile-local row
        float cv = acc[i][j][r] + bv;
        if (act) {  // fast GELU: x * sigmoid(1.5958x + 0.07135x^3)
          float t = cv * (1.5957692f + 0.0713548f * cv * cv);
          cv = cv / (1.f + __expf(-t));
        }
        if (!vmode)
          Cl[row * BN + (((col >> 3) ^ (row & 7)) << 3) + (col & 7)] = f2b(cv);
        else
          Cl[col * BM + (((row >> 3) ^ (col & 7)) << 3) + (row & 7)] = f2b(cv);
      }
    }
  }
  __syncthreads();
  if (!vmode) {
    constexpr int TOT = BM * BN / 8;
    for (int e = tid; e < TOT; e += 256) {
      int rr = e / (BN / 8), c8 = e % (BN / 8);
      ushort8 u = *(const ushort8*)(Cl + rr * BN + ((c8 ^ (rr & 7)) << 3));
      size_t off = (size_t)(bm + rr) * cs + bn + c8 * 8;
      if (resid) {
        ushort8 rv = *(const ushort8*)(resid + off);
        for (int t = 0; t < 8; t++) u[t] = f2b(b2f(u[t]) + b2f(rv[t]));
      }
      *(ushort8*)(C + off) = u;
    }
  } else {
    constexpr int TOT = BM * BN / 8;
    for (int e = tid; e < TOT; e += 256) {
      int cc = e / (BM / 8), t8 = e % (BM / 8);
      ushort8 u = *(const ushort8*)(Cl + cc * BM + ((t8 ^ (cc & 7)) << 3));
      int hd = bn - 1024 + cc;
      int rowg = bm + t8 * 8;
      int bb = rowg >> 11, tokin = rowg & 2047;
      *(ushort8*)(vTp + ((size_t)(bb * 512 + hd)) * 2048 + tokin) = u;
    }
  }
}

// ---------------------------------------------------------------------------
// k_attn: banded MFMA attention, fragment-direct global loads with 1-deep
// register prefetch (19.5 KB LDS, low VGPR -> 8 blocks/CU; do NOT stage K
// in LDS: R7 showed 56 KB -> 2 blocks/CU regressed 62->100us).
// ---------------------------------------------------------------------------
__global__ __launch_bounds__(256) void k_attn(
    const unsigned short* __restrict__ qk,
    const unsigned short* __restrict__ vT, unsigned short* __restrict__ o) {
  constexpr int SSTR = 304;
  __shared__ __align__(16) unsigned short S[32 * SSTR];
  int id = blockIdx.x;
  int xcd = id & 7, rr_ = id >> 3;
  int p = xcd * 8 + (rr_ & 7);
  int h = (rr_ >> 3) & 7;
  int b = rr_ >> 6;
  int tid = threadIdx.x, lane = tid & 63, w = tid >> 6;
  int lane15 = lane & 15, q = lane >> 4;
  int p0 = max(0, p - WIN), p1 = min(P - 1, p + WIN);
  int nk = (p1 - p0 + 1) * 32;     // multiple of 32, in [160,288]
  int ntiles = nk >> 4;
  size_t base = (size_t)b * L;
  int mtile = w & 1;
  const unsigned short* qrow =
      qk + (base + p * 32 + mtile * 16 + lane15) * 1024 + h * 64 + q * 8;
  short8 aq0 = *(const short8*)(qrow);
  short8 aq1 = *(const short8*)(qrow + 32);
  const unsigned short* kbase =
      qk + (base + p0 * 32) * 1024 + 512 + h * 64 + q * 8;
  {
    int nt = w >> 1;
    const unsigned short* kr = kbase + (size_t)(nt * 16 + lane15) * 1024;
    short8 kc0 = *(const short8*)(kr);
    short8 kc1 = *(const short8*)(kr + 32);
    for (; nt < ntiles; nt += 2) {
      short8 kn0, kn1;
      if (nt + 2 < ntiles) {
        const unsigned short* kr2 =
            kbase + (size_t)((nt + 2) * 16 + lane15) * 1024;
        kn0 = *(const short8*)(kr2);
        kn1 = *(const short8*)(kr2 + 32);
      }
      float4v s4 = 0;
      s4 = __builtin_amdgcn_mfma_f32_16x16x32_bf16(aq0, kc0, s4, 0, 0, 0);
      s4 = __builtin_amdgcn_mfma_f32_16x16x32_bf16(aq1, kc1, s4, 0, 0, 0);
      for (int r = 0; r < 4; r++)
        S[(mtile * 16 + q * 4 + r) * SSTR + nt * 16 + lane15] =
            f2b(s4[r] * 0.125f);
      kc0 = kn0; kc1 = kn1;
    }
  }
  __syncthreads();
  // softmax without max-sub (|scores| small), b128 LDS IO
  {
    int row = tid >> 3, c = tid & 7;
    ushort8 eb[5];
    float sum = 0.f;
    for (int k = 0; k < 5; k++) {
      int j0 = c * 8 + k * 64;
      if (j0 < nk) {
        ushort8 u = *(const ushort8*)(S + row * SSTR + j0);
        ushort8 e8;
        for (int t = 0; t < 8; t++) {
          float e = __expf(b2f(u[t]));
          sum += e;
          e8[t] = f2b(e);
        }
        eb[k] = e8;
      }
    }
    for (int off = 1; off < 8; off <<= 1) sum += __shfl_xor(sum, off);
    float inv = 1.f / sum;
    for (int k = 0; k < 5; k++) {
      int j0 = c * 8 + k * 64;
      if (j0 < nk) {
        ushort8 e8 = eb[k], u;
        for (int t = 0; t < 8; t++) u[t] = f2b(b2f(e8[t]) * inv);
        *(ushort8*)(S + row * SSTR + j0) = u;
      }
    }
  }
  __syncthreads();
  int ntb = (w >> 1) * 2;
  int nkt = nk >> 5;
  const unsigned short* vb0 =
      vT + (size_t)(b * 512 + h * 64 + ntb * 16 + lane15) * 2048 + p0 * 32 +
      q * 8;
  const unsigned short* vb1 = vb0 + 16 * 2048;
  const unsigned short* prow = S + (mtile * 16 + lane15) * SSTR + q * 8;
  float4v oa0 = 0, oa1 = 0;
  short8 ap = *(const short8*)(prow);
  short8 v0 = *(const short8*)(vb0);
  short8 v1 = *(const short8*)(vb1);
  for (int kt = 0; kt < nkt; kt++) {
    short8 apN, v0N, v1N;
    if (kt + 1 < nkt) {
      apN = *(const short8*)(prow + (kt + 1) * 32);
      v0N = *(const short8*)(vb0 + (kt + 1) * 32);
      v1N = *(const short8*)(vb1 + (kt + 1) * 32);
    }
    oa0 = __builtin_amdgcn_mfma_f32_16x16x32_bf16(ap, v0, oa0, 0, 0, 0);
    oa1 = __builtin_amdgcn_mfma_f32_16x16x32_bf16(ap, v1, oa1, 0, 0, 0);
    ap = apN; v0 = v0N; v1 = v1N;
  }
  __syncthreads();
  for (int r = 0; r < 4; r++) {
    S[(mtile * 16 + q * 4 + r) * 72 + ntb * 16 + lane15] = f2b(oa0[r]);
    S[(mtile * 16 + q * 4 + r) * 72 + (ntb + 1) * 16 + lane15] = f2b(oa1[r]);
  }
  __syncthreads();
  {
    int row = tid >> 3, c8 = tid & 7;
    ushort8 val = *(const ushort8*)(S + row * 72 + c8 * 8);
    *(ushort8*)(o + (base + p * 32 + row) * 512 + h * 64 + c8 * 8) = val;
  }
}

// ---------------------------------------------------------------------------
// k_ln: layernorm over D=512 per token, bf16 in/out. 4 rows per block.
// ---------------------------------------------------------------------------
__global__ void k_ln(const unsigned short* __restrict__ x, const void* g,
                     const void* bta, unsigned short* __restrict__ out,
                     const int* flags, int goff) {
  int bf = flags[0];
  int row = blockIdx.x * 4 + (threadIdx.x >> 6);
  int lane = threadIdx.x & 63;
  ushort8 u = *(const ushort8*)(x + (size_t)row * D + lane * 8);
  float v[8]; float s = 0.f, s2 = 0.f;
  for (int t = 0; t < 8; t++) {
    v[t] = b2f(u[t]); s += v[t]; s2 += v[t] * v[t];
  }
  for (int off = 32; off; off >>= 1) {
    s += __shfl_xor(s, off); s2 += __shfl_xor(s2, off);
  }
  float m = s / (float)D;
  float inv = rsqrtf(s2 / (float)D - m * m + 1e-5f);
  ushort8 ou;
  for (int t = 0; t < 8; t++) {
    int c = lane * 8 + t;
    ou[t] = f2b((v[t] - m) * inv * ldf(g, goff + c, bf) + ldf(bta, goff + c, bf));
  }
  *(ushort8*)(out + (size_t)row * D + lane * 8) = ou;
}

// ---------------------------------------------------------------------------
// k_lnloss: fused final LN + recon head (MFMA) + masked MSE.
// ---------------------------------------------------------------------------
__global__ __launch_bounds__(128) void k_lnloss(
    const unsigned short* __restrict__ tok, const float* __restrict__ lnw,
    const unsigned short* __restrict__ WpT, const float* __restrict__ patches,
    const float* __restrict__ stdev, const int* __restrict__ mask_i,
    float* scal) {
  constexpr int RS = 520;  // padded LDS row stride (elements)
  __shared__ __align__(16) unsigned short As[32 * RS];
  __shared__ __align__(16) unsigned short Bs[16 * RS];
  int bpI = blockIdx.x; int b = bpI >> 6, p = bpI & 63;
  int tid = threadIdx.x;
  int row = tid >> 2, cg = tid & 3;   // 4 threads per token row
  size_t tokbase = (size_t)(b * L + p * 32);
  float s = 0.f, s2 = 0.f;
  for (int i = 0; i < 16; i++) {
    int c = cg + i * 4;
    ushort8 u = *(const ushort8*)(tok + (tokbase + row) * D + c * 8);
    for (int t = 0; t < 8; t++) { float v = b2f(u[t]); s += v; s2 += v * v; }
  }
  s += __shfl_xor(s, 1); s += __shfl_xor(s, 2);
  s2 += __shfl_xor(s2, 1); s2 += __shfl_xor(s2, 2);
  float m = s / (float)D;
  float inv = rsqrtf(s2 / (float)D - m * m + 1e-5f);
  for (int i = 0; i < 16; i++) {
    int c = cg + i * 4;
    ushort8 u = *(const ushort8*)(tok + (tokbase + row) * D + c * 8);
    ushort8 o;
    for (int t = 0; t < 8; t++) {
      int col = c * 8 + t;
      o[t] = f2b((b2f(u[t]) - m) * inv * lnw[col] + lnw[512 + col]);
    }
    *(ushort8*)(As + row * RS + c * 8) = o;
  }
  for (int e = tid; e < 16 * 64; e += 128) {
    int r = e >> 6, c = e & 63;
    *(ushort8*)(Bs + r * RS + c * 8) = *(const ushort8*)(WpT + r * 512 + c * 8);
  }
  __syncthreads();
  int w = tid >> 6, lane = tid & 63, lane15 = lane & 15, q = lane >> 4;
  float4v acc = 0;
  for (int kt = 0; kt < 16; kt++) {
    short8 a = *(const short8*)(As + (w * 16 + lane15) * RS + kt * 32 + q * 8);
    short8 bfr = *(const short8*)(Bs + lane15 * RS + kt * 32 + q * 8);
    acc = __builtin_amdgcn_mfma_f32_16x16x32_bf16(a, bfr, acc, 0, 0, 0);
  }
  float local = 0.f;
  int t = lane15;
  for (int r = 0; r < 4; r++) {
    int v = w * 16 + q * 4 + r;
    int tokidx = b * 2048 + p * 32 + v;
    if (mask_i[tokidx]) {
      float recon = acc[r] + lnw[1024 + t];
      float diff = recon - patches[(size_t)tokidx * 16 + t];
      float sc = stdev[b * 32 + v];
      local += sc * sc * diff * diff;
    }
  }
  for (int off = 32; off; off >>= 1) local += __shfl_xor(local, off);
  if (lane == 0) atomicAdd(&scal[0], local);
}

__global__ void k_final(const float* scal, const int* flags, unsigned* out) {
  float denom = (float)flags[1] * (float)PL;
  if (denom == 0.f) denom = 1.f;
  float loss = scal[0] / denom;
  unsigned fb = __float_as_uint(loss);
  unsigned u = (fb + 0x7FFFu + ((fb >> 16) & 1u)) >> 16;
  out[0] = (u << 16) | u;
}

}  // namespace

extern "C" void kernel_launch(void* const* d_in, const int* in_sizes, int n_in,
                              void* d_out, int out_size, void* d_ws,
                              size_t ws_size, hipStream_t stream) {
  const void* x_enc = d_in[0];
  const void* maskp = d_in[1];
  const void* We = d_in[2];  const void* be_ = d_in[3];
  const void* Wq = d_in[4];  const void* bq = d_in[5];
  const void* Wk = d_in[6];  const void* bk = d_in[7];
  const void* Wv = d_in[8];  const void* bv = d_in[9];
  const void* Wo = d_in[10]; const void* bo_ = d_in[11];
  const void* W1 = d_in[12]; const void* b1 = d_in[13];
  const void* W2 = d_in[14]; const void* b2 = d_in[15];
  const void* g1 = d_in[16]; const void* be1 = d_in[17];
  const void* g2 = d_in[18]; const void* be2 = d_in[19];
  const void* gf = d_in[20]; const void* bff = d_in[21];
  const void* Wp = d_in[22]; const void* bp = d_in[23];

  constexpr size_t MB = 1u << 20;
  char* w = (char*)d_ws;
  int*   mask_i  = (int*)w;                        // 32 KB
  int*   flags   = (int*)(w + 32768);
  float* scal    = (float*)(w + 32896);
  float* means   = (float*)(w + 33024);
  float* stdev   = (float*)(w + 33600);
  float* biasf   = (float*)(w + 36864);            // 73728 B -> ends 110592
  float* lnw     = (float*)(w + 114688);           // 4160 B
  float* patches = (float*)(w + 131072);           // 512 KB -> ends 655360
  unsigned short* WpT = (unsigned short*)(w + 655360);    // 16 KB
  unsigned short* qkvT = (unsigned short*)(w + 1 * MB);   // 6 MB
  unsigned short* WoT  = (unsigned short*)(w + 7 * MB);   // 2 MB
  unsigned short* W1T  = (unsigned short*)(w + 9 * MB);   // 8 MB
  unsigned short* W2T  = (unsigned short*)(w + 17 * MB);  // 8 MB
  unsigned short* tok  = (unsigned short*)(w + 25 * MB);  // 8 MB
  unsigned short* tmp  = (unsigned short*)(w + 33 * MB);  // 8 MB
  unsigned short* ob   = (unsigned short*)(w + 41 * MB);  // 8 MB
  unsigned short* qk   = (unsigned short*)(w + 49 * MB);  // 16 MB -> ends 65
  unsigned short* vTb  = (unsigned short*)(w + 73 * MB);  // 8 MB -> ends 81
  unsigned short* hidden = ob;   // 32 MB alias over ob+qk (dead by FFN1)

  k_setup<<<1, 256, 0, stream>>>(gf, maskp, mask_i, flags, scal);
  k_prep<<<141, 256, 0, stream>>>(x_enc, bq, bk, bv, bo_, b1, b2, gf, bff, Wp,
                                  bp, flags, means, stdev, biasf, lnw, WpT);
  k_transpose_all<<<12288, 256, 0, stream>>>(Wq, Wk, Wv, Wo, W1, W2, qkvT, WoT,
                                             W1T, W2T, flags);
  k_embed<<<M, 128, 0, stream>>>(x_enc, We, be_, flags, mask_i, means, stdev,
                                 patches, tok);
  for (int l = 0; l < 4; l++) {
    k_gemm<128, 64, 32><<<1536, 256, 0, stream>>>(
        tok, qkvT + (size_t)l * 786432, biasf + l * 1536, nullptr, qk, vTb,
        1024, 512, 0, 24);
    k_attn<<<2048, 256, 0, stream>>>(qk, vTb, ob);
    k_gemm<64, 64, 16><<<1024, 256, 0, stream>>>(
        ob, WoT + (size_t)l * 262144, biasf + 6144 + l * 512, tok, tmp,
        nullptr, 512, 512, 0, 8);
    k_ln<<<M / 4, 256, 0, stream>>>(tmp, g1, be1, tok, flags, l * 512);
    k_gemm<128, 64, 32><<<2048, 256, 0, stream>>>(
        tok, W1T + (size_t)l * 1048576, biasf + 8192 + l * 2048, nullptr,
        hidden, nullptr, 2048, 512, 1, 32);
    k_gemm<64, 64, 16><<<1024, 256, 0, stream>>>(
        hidden, W2T + (size_t)l * 1048576, biasf + 16384 + l * 512, tok, tmp,
        nullptr, 512, 2048, 0, 8);
    k_ln<<<M / 4, 256, 0, stream>>>(tmp, g2, be2, tok, flags, l * 512);
  }
  k_lnloss<<<Bn * P, 128, 0, stream>>>(tok, lnw, WpT, patches, stdev, mask_i,
                                       scal);
  k_final<<<1, 1, 0, stream>>>(scal, flags, (unsigned*)d_out);
}

// Round 11
// 916.261 us; speedup vs baseline: 1.3292x; 1.0079x over previous
//
#include <hip/hip_runtime.h>
#include <hip/hip_bf16.h>

#define DEV __device__ __forceinline__

namespace {

constexpr int Bn  = 4, SEQ = 1024, NV = 32, PL = 16, D = 512, H = 8, DFF = 2048;
constexpr int P   = SEQ / PL;    // 64 patches
constexpr int L   = P * NV;      // 2048 tokens per batch
constexpr int M   = Bn * L;      // 8192 total token rows
constexpr int WIN = 4;

using short8   = __attribute__((ext_vector_type(8))) short;
using ushort8  = __attribute__((ext_vector_type(8))) unsigned short;
using float4v  = __attribute__((ext_vector_type(4))) float;

DEV float b2f(unsigned short u) { return __uint_as_float(((unsigned)u) << 16); }
DEV unsigned short f2b(float f) {   // RNE (used where bias matters)
  unsigned fb = __float_as_uint(f);
  return (unsigned short)((fb + 0x7FFFu + ((fb >> 16) & 1u)) >> 16);
}
DEV unsigned short f2bt(float f) {  // truncation: 1 VALU op
  return (unsigned short)(__float_as_uint(f) >> 16);
}
// flag-dispatched float load from an input tensor: bf=1 -> bf16, 0 -> fp32
DEV float ldf(const void* p, size_t idx, int bf) {
  if (bf) return b2f(((const unsigned short*)p)[idx]);
  return ((const float*)p)[idx];
}
// async global->LDS 16B: lds dest = wave-uniform base + lane*16
DEV void gll16(const void* gp, void* lp) {
  __builtin_amdgcn_global_load_lds(
      (const __attribute__((address_space(1))) void*)gp,
      (__attribute__((address_space(3))) void*)lp, 16, 0, 0);
}

// ---------------------------------------------------------------------------
// k_setup: detect float dtype + mask format, canonicalize mask, count masked.
// ---------------------------------------------------------------------------
__global__ void k_setup(const void* gf, const void* mask_raw, int* mask_i,
                        int* flags, float* scal) {
  __shared__ int s_gt1, s_oth, s_cnt;
  int tid = threadIdx.x;
  if (tid == 0) { s_gt1 = 0; s_oth = 0; s_cnt = 0; }
  __syncthreads();
  const unsigned* mw = (const unsigned*)mask_raw;
  int gt1 = 0, oth = 0;
  for (int i = tid; i < 2048; i += 256) {
    unsigned w = mw[i];
    if (w > 1u) { gt1 = 1; if (w != 0x3F800000u) oth = 1; }
  }
  if (gt1) atomicOr(&s_gt1, 1);
  if (oth) atomicOr(&s_oth, 1);
  __syncthreads();
  int fmt = (!s_gt1) ? 0 : (!s_oth ? 1 : 2);  // 0=int32, 1=f32, 2=bytes
  int cnt = 0;
  for (int i = tid; i < Bn * P * NV; i += 256) {
    int m;
    if (fmt == 0)      m = ((const int*)mask_raw)[i] != 0;
    else if (fmt == 1) m = ((const float*)mask_raw)[i] != 0.0f;
    else               m = ((const unsigned char*)mask_raw)[i] != 0;
    mask_i[i] = m; cnt += m;
  }
  atomicAdd(&s_cnt, cnt);
  __syncthreads();
  if (tid == 0) {
    unsigned w = *(const unsigned*)gf;
    flags[0] = ((w & 0xFFFFu) == 0x3F80u) ? 1 : 0;
    flags[1] = s_cnt;
    scal[0] = 0.f;
  }
}

// ---------------------------------------------------------------------------
// k_prep: blocks 0..31 -> per-(b,v) stats; blocks 32.. -> gather biases,
// final-LN weights (fp32), b_proj (fp32), and WpT (bf16 [t][d]).
// ---------------------------------------------------------------------------
__global__ void k_prep(const void* x, const void* bq, const void* bk,
                       const void* bv, const void* bo, const void* b1,
                       const void* b2, const void* gf, const void* bff,
                       const void* Wp, const void* bp, const int* flags,
                       float* means, float* stdev, float* biasf, float* lnw,
                       unsigned short* WpT) {
  int bf = flags[0];
  int tid = threadIdx.x;
  if (blockIdx.x < 32) {
    int bv_ = blockIdx.x * 4 + (tid >> 6);
    int b = bv_ >> 5, v = bv_ & 31;
    int lane = tid & 63;
    float s = 0.f, s2 = 0.f;
    for (int t = lane; t < SEQ; t += 64) {
      float val = ldf(x, (size_t)b * SEQ * NV + (size_t)t * NV + v, bf);
      s += val; s2 += val * val;
    }
    for (int off = 32; off; off >>= 1) {
      s += __shfl_xor(s, off); s2 += __shfl_xor(s2, off);
    }
    if (lane == 0) {
      float m = s / (float)SEQ;
      means[bv_] = m;
      stdev[bv_] = sqrtf(s2 / (float)SEQ - m * m + 1e-5f);
    }
    return;
  }
  int i = (blockIdx.x - 32) * 256 + tid;
  if (i < 18432) {
    int l = i / 4608, r = i % 4608;
    if (r < 1536) {
      float v = (r < 512) ? ldf(bq, l * 512 + r, bf)
              : (r < 1024) ? ldf(bk, l * 512 + r - 512, bf)
                           : ldf(bv, l * 512 + r - 1024, bf);
      biasf[l * 1536 + r] = v;
    } else if (r < 2048) {
      biasf[6144 + l * 512 + (r - 1536)] = ldf(bo, l * 512 + r - 1536, bf);
    } else if (r < 4096) {
      biasf[8192 + l * 2048 + (r - 2048)] = ldf(b1, l * 2048 + r - 2048, bf);
    } else {
      biasf[16384 + l * 512 + (r - 4096)] = ldf(b2, l * 512 + r - 4096, bf);
    }
  } else if (i < 19456) {
    int j = i - 18432;
    lnw[j] = (j < 512) ? ldf(gf, j, bf) : ldf(bff, j - 512, bf);
  } else if (i < 19472) {
    lnw[1024 + (i - 19456)] = ldf(bp, i - 19456, bf);
  } else if (i < 27664) {
    int j = i - 19472; int t = j >> 9, d = j & 511;
    WpT[j] = f2b(ldf(Wp, d * 16 + t, bf));
  }
}

// ---------------------------------------------------------------------------
// k_transpose_all: all 6 weight transposes in one dispatch.
// dst[l][n][k] (bf16) = src[l][k][n]. 32x32 LDS tile per block.
// ---------------------------------------------------------------------------
__global__ void k_transpose_all(const void* Wq, const void* Wk, const void* Wv,
                                const void* Wo, const void* W1, const void* W2,
                                unsigned short* qkvT, unsigned short* WoT,
                                unsigned short* W1T, unsigned short* W2T,
                                const int* flags) {
  int bf = flags[0];
  int id = blockIdx.x;
  const void* src; unsigned short* dst;
  int Kd, Nd, l, n0, k0, dstOff = 0;
  size_t srcLS, dstLS;
  if (id < 4096) {
    int tensor = id >> 10, rem = id & 1023;
    l = rem >> 8; int t = rem & 255;
    n0 = (t & 15) * 32; k0 = (t >> 4) * 32;
    Kd = 512; Nd = 512; srcLS = 262144;
    if (tensor == 0)      { src = Wq; dst = qkvT; dstLS = 786432; dstOff = 0; }
    else if (tensor == 1) { src = Wk; dst = qkvT; dstLS = 786432; dstOff = 262144; }
    else if (tensor == 2) { src = Wv; dst = qkvT; dstLS = 786432; dstOff = 524288; }
    else                  { src = Wo; dst = WoT;  dstLS = 262144; }
  } else if (id < 8192) {
    int rem = id - 4096; l = rem >> 10; int t = rem & 1023;
    n0 = (t & 63) * 32; k0 = (t >> 6) * 32;
    Kd = 512; Nd = 2048; srcLS = 1048576; src = W1; dst = W1T; dstLS = 1048576;
  } else {
    int rem = id - 8192; l = rem >> 10; int t = rem & 1023;
    n0 = (t & 15) * 32; k0 = (t >> 4) * 32;
    Kd = 2048; Nd = 512; srcLS = 1048576; src = W2; dst = W2T; dstLS = 1048576;
  }
  int tx = threadIdx.x & 31, ty = threadIdx.x >> 5;
  __shared__ float tile[32][33];
  for (int rr = ty; rr < 32; rr += 8)
    tile[rr][tx] =
        ldf(src, (size_t)l * srcLS + (size_t)(k0 + rr) * Nd + n0 + tx, bf);
  __syncthreads();
  for (int rr = ty; rr < 32; rr += 8)
    dst[(size_t)l * dstLS + dstOff + (size_t)(n0 + rr) * Kd + k0 + tx] =
        f2b(tile[tx][rr]);
}

// ---------------------------------------------------------------------------
// k_embed: patchify + instance-normalize, write patches (fp32) and embedded
// tokens (bf16), zeroing masked tokens. One block (128 thr) per token.
// ---------------------------------------------------------------------------
__global__ void k_embed(const void* x, const void* We, const void* be,
                        const int* flags, const int* mask_i,
                        const float* means, const float* stdev,
                        float* patches, unsigned short* tok) {
  int idx = blockIdx.x;
  int b = idx >> 11, pv = idx & 2047, p = pv >> 5, v = pv & 31;
  int bf = flags[0];
  __shared__ float pvs[PL];
  int tid = threadIdx.x;
  float m = means[b * NV + v], sd = stdev[b * NV + v];
  if (tid < PL) {
    float val =
        (ldf(x, (size_t)b * SEQ * NV + (size_t)(p * PL + tid) * NV + v, bf) -
         m) / sd;
    pvs[tid] = val;
    patches[(size_t)idx * PL + tid] = val;
  }
  __syncthreads();
  int masked = mask_i[idx];
  for (int d = tid; d < D; d += 128) {
    float acc = ldf(be, d, bf);
    for (int t = 0; t < PL; t++) acc += pvs[t] * ldf(We, t * D + d, bf);
    tok[(size_t)idx * D + d] = masked ? f2b(0.f) : f2b(acc);
  }
}

// ---------------------------------------------------------------------------
// k_gemm<BM,BN,WN>: C = act(A @ W^T' + bias [+resid]) in bf16. BK=64.
// Linear grid, XCD-swizzled. Epilogue through LDS for coalesced ushort8 IO.
// vTp != null (QKV): bn >= 1024 tiles are V (staged transposed -> vT); q
// tiles (bn < 512) are pre-scaled by SCALE=0.125 so attention needs no scale.
// Output packs use 1-op truncation (absmax margin is huge).
// ---------------------------------------------------------------------------
template <int BM, int BN, int WN>
__global__ __launch_bounds__(256) void k_gemm(
    const unsigned short* __restrict__ A, const unsigned short* __restrict__ W,
    const float* __restrict__ bias, const unsigned short* __restrict__ resid,
    unsigned short* __restrict__ C, unsigned short* __restrict__ vTp, int cs,
    int Kk, int act, int nbn) {
  constexpr int FI = 4, FJ = WN / 16, NWN = BN / WN;
  __shared__ __align__(16) char sm[BM * 128 + BN * 128];
  char* As = sm;
  char* Bs = sm + BM * 128;
  unsigned short* Cl = (unsigned short*)sm;
  int tid = threadIdx.x, lane = tid & 63, w = tid >> 6;
  int lane15 = lane & 15, q = lane >> 4;
  int wm = w / NWN, wn = w % NWN;
  int id = blockIdx.x;
  int xcd = id & 7, loc = id >> 3;
  int bn = (loc % nbn) * BN;
  int bm = (xcd * ((int)(gridDim.x >> 3) / nbn) + loc / nbn) * BM;
  int lrow = lane >> 3, lc = lane & 7;
  float4v acc[FI][FJ];
  for (int i = 0; i < FI; i++)
    for (int j = 0; j < FJ; j++) acc[i][j] = 0;
  for (int k0 = 0; k0 < Kk; k0 += 64) {
    if (k0) __syncthreads();
    for (int i = w; i < BM / 8; i += 4) {
      int row = i * 8 + lrow;
      gll16(A + (size_t)(bm + row) * Kk + k0 + ((lc ^ (row & 7)) << 3),
            As + i * 1024);
    }
    for (int i = w; i < BN / 8; i += 4) {
      int row = i * 8 + lrow;
      gll16(W + (size_t)(bn + row) * Kk + k0 + ((lc ^ (row & 7)) << 3),
            Bs + i * 1024);
    }
    __syncthreads();
    short8 a[2][FI], b[2][FJ];
    for (int h = 0; h < 2; h++) {
      for (int i = 0; i < FI; i++) {
        int rr = wm * 64 + i * 16 + lane15;
        a[h][i] =
            *(const short8*)(As + rr * 128 + (((h * 4 + q) ^ (rr & 7)) << 4));
      }
      for (int j = 0; j < FJ; j++) {
        int rr = wn * WN + j * 16 + lane15;
        b[h][j] =
            *(const short8*)(Bs + rr * 128 + (((h * 4 + q) ^ (rr & 7)) << 4));
      }
    }
    for (int h = 0; h < 2; h++)
      for (int i = 0; i < FI; i++)
        for (int j = 0; j < FJ; j++)
          acc[i][j] = __builtin_amdgcn_mfma_f32_16x16x32_bf16(
              a[h][i], b[h][j], acc[i][j], 0, 0, 0);
  }
  // ---- epilogue through LDS ----
  int vmode = (vTp != nullptr) && (bn >= 1024);
  float oscale = (vTp != nullptr && bn < 512) ? 0.125f : 1.0f;  // q pre-scale
  __syncthreads();  // all MFMAs done reading As/Bs
  for (int i = 0; i < FI; i++) {
    for (int j = 0; j < FJ; j++) {
      int col = wn * WN + j * 16 + lane15;        // tile-local col
      float bv = bias[bn + col];
      for (int r = 0; r < 4; r++) {
        int row = wm * 64 + i * 16 + q * 4 + r;   // tile-local row
        float cv = (acc[i][j][r] + bv) * oscale;
        if (act) {  // fast GELU: x * sigmoid(1.5958x + 0.07135x^3)
          float t = cv * (1.5957692f + 0.0713548f * cv * cv);
          cv = cv / (1.f + __expf(-t));
        }
        if (!vmode)
          Cl[row * BN + (((col >> 3) ^ (row & 7)) << 3) + (col & 7)] = f2bt(cv);
        else
          Cl[col * BM + (((row >> 3) ^ (col & 7)) << 3) + (row & 7)] = f2bt(cv);
      }
    }
  }
  __syncthreads();
  if (!vmode) {
    constexpr int TOT = BM * BN / 8;
    for (int e = tid; e < TOT; e += 256) {
      int rr = e / (BN / 8), c8 = e % (BN / 8);
      ushort8 u = *(const ushort8*)(Cl + rr * BN + ((c8 ^ (rr & 7)) << 3));
      size_t off = (size_t)(bm + rr) * cs + bn + c8 * 8;
      if (resid) {
        ushort8 rv = *(const ushort8*)(resid + off);
        for (int t = 0; t < 8; t++) u[t] = f2bt(b2f(u[t]) + b2f(rv[t]));
      }
      *(ushort8*)(C + off) = u;
    }
  } else {
    constexpr int TOT = BM * BN / 8;
    for (int e = tid; e < TOT; e += 256) {
      int cc = e / (BM / 8), t8 = e % (BM / 8);
      ushort8 u = *(const ushort8*)(Cl + cc * BM + ((t8 ^ (cc & 7)) << 3));
      int hd = bn - 1024 + cc;
      int rowg = bm + t8 * 8;
      int bb = rowg >> 11, tokin = rowg & 2047;
      *(ushort8*)(vTp + ((size_t)(bb * 512 + hd)) * 2048 + tokin) = u;
    }
  }
}

// ---------------------------------------------------------------------------
// k_attn: banded MFMA attention, fragment-direct global loads with 2-deep
// K prefetch (19.5 KB LDS, ~40 VGPR -> 8 blocks/CU; do NOT stage K in LDS:
// R7's 56 KB dropped to 2 blocks/CU and regressed 62->100us).
// q is pre-scaled by 0.125 in the QKV GEMM; softmax skips max-sub (|s|<~5).
// P and O packs use 1-op truncation.
// ---------------------------------------------------------------------------
__global__ __launch_bounds__(256) void k_attn(
    const unsigned short* __restrict__ qk,
    const unsigned short* __restrict__ vT, unsigned short* __restrict__ o) {
  constexpr int SSTR = 304;
  __shared__ __align__(16) unsigned short S[32 * SSTR];
  int id = blockIdx.x;
  int xcd = id & 7, rr_ = id >> 3;
  int p = xcd * 8 + (rr_ & 7);
  int h = (rr_ >> 3) & 7;
  int b = rr_ >> 6;
  int tid = threadIdx.x, lane = tid & 63, w = tid >> 6;
  int lane15 = lane & 15, q = lane >> 4;
  int p0 = max(0, p - WIN), p1 = min(P - 1, p + WIN);
  int nk = (p1 - p0 + 1) * 32;     // multiple of 32, in [160,288]
  int ntiles = nk >> 4;
  size_t base = (size_t)b * L;
  int mtile = w & 1;
  const unsigned short* qrow =
      qk + (base + p * 32 + mtile * 16 + lane15) * 1024 + h * 64 + q * 8;
  short8 aq0 = *(const short8*)(qrow);
  short8 aq1 = *(const short8*)(qrow + 32);
  const unsigned short* kbase =
      qk + (base + p0 * 32) * 1024 + 512 + h * 64 + q * 8;
  // phase A: S = Q K^T (q pre-scaled), 2-deep K prefetch
  {
    int nt = w >> 1;
    const unsigned short* kr = kbase + (size_t)(nt * 16 + lane15) * 1024;
    short8 c0 = *(const short8*)(kr);
    short8 c1 = *(const short8*)(kr + 32);
    short8 n0, n1;
    if (nt + 2 < ntiles) {
      kr = kbase + (size_t)((nt + 2) * 16 + lane15) * 1024;
      n0 = *(const short8*)(kr);
      n1 = *(const short8*)(kr + 32);
    }
    for (; nt < ntiles; nt += 2) {
      short8 m0, m1;
      if (nt + 4 < ntiles) {
        kr = kbase + (size_t)((nt + 4) * 16 + lane15) * 1024;
        m0 = *(const short8*)(kr);
        m1 = *(const short8*)(kr + 32);
      }
      float4v s4 = 0;
      s4 = __builtin_amdgcn_mfma_f32_16x16x32_bf16(aq0, c0, s4, 0, 0, 0);
      s4 = __builtin_amdgcn_mfma_f32_16x16x32_bf16(aq1, c1, s4, 0, 0, 0);
      for (int r = 0; r < 4; r++)
        S[(mtile * 16 + q * 4 + r) * SSTR + nt * 16 + lane15] = f2b(s4[r]);
      c0 = n0; c1 = n1; n0 = m0; n1 = m1;
    }
  }
  __syncthreads();
  // phase B: softmax without max-sub, b128 LDS IO, trunc P pack
  {
    int row = tid >> 3, c = tid & 7;
    ushort8 eb[5];
    float sum = 0.f;
    for (int k = 0; k < 5; k++) {
      int j0 = c * 8 + k * 64;
      if (j0 < nk) {
        ushort8 u = *(const ushort8*)(S + row * SSTR + j0);
        ushort8 e8;
        for (int t = 0; t < 8; t++) {
          float e = __expf(b2f(u[t]));
          sum += e;
          e8[t] = f2bt(e);
        }
        eb[k] = e8;
      }
    }
    for (int off = 1; off < 8; off <<= 1) sum += __shfl_xor(sum, off);
    float inv = 1.f / sum;
    for (int k = 0; k < 5; k++) {
      int j0 = c * 8 + k * 64;
      if (j0 < nk) {
        ushort8 e8 = eb[k], u;
        for (int t = 0; t < 8; t++) u[t] = f2bt(b2f(e8[t]) * inv);
        *(ushort8*)(S + row * SSTR + j0) = u;
      }
    }
  }
  __syncthreads();
  // phase C: O = P V, V fragment-direct from vT with 1-deep prefetch
  int ntb = (w >> 1) * 2;
  int nkt = nk >> 5;
  const unsigned short* vb0 =
      vT + (size_t)(b * 512 + h * 64 + ntb * 16 + lane15) * 2048 + p0 * 32 +
      q * 8;
  const unsigned short* vb1 = vb0 + 16 * 2048;
  const unsigned short* prow = S + (mtile * 16 + lane15) * SSTR + q * 8;
  float4v oa0 = 0, oa1 = 0;
  short8 ap = *(const short8*)(prow);
  short8 v0 = *(const short8*)(vb0);
  short8 v1 = *(const short8*)(vb1);
  for (int kt = 0; kt < nkt; kt++) {
    short8 apN, v0N, v1N;
    if (kt + 1 < nkt) {
      apN = *(const short8*)(prow + (kt + 1) * 32);
      v0N = *(const short8*)(vb0 + (kt + 1) * 32);
      v1N = *(const short8*)(vb1 + (kt + 1) * 32);
    }
    oa0 = __builtin_amdgcn_mfma_f32_16x16x32_bf16(ap, v0, oa0, 0, 0, 0);
    oa1 = __builtin_amdgcn_mfma_f32_16x16x32_bf16(ap, v1, oa1, 0, 0, 0);
    ap = apN; v0 = v0N; v1 = v1N;
  }
  __syncthreads();
  for (int r = 0; r < 4; r++) {
    S[(mtile * 16 + q * 4 + r) * 72 + ntb * 16 + lane15] = f2bt(oa0[r]);
    S[(mtile * 16 + q * 4 + r) * 72 + (ntb + 1) * 16 + lane15] = f2bt(oa1[r]);
  }
  __syncthreads();
  {
    int row = tid >> 3, c8 = tid & 7;
    ushort8 val = *(const ushort8*)(S + row * 72 + c8 * 8);
    *(ushort8*)(o + (base + p * 32 + row) * 512 + h * 64 + c8 * 8) = val;
  }
}

// ---------------------------------------------------------------------------
// k_ln: layernorm over D=512 per token, bf16 in/out. 4 rows per block.
// ---------------------------------------------------------------------------
__global__ void k_ln(const unsigned short* __restrict__ x, const void* g,
                     const void* bta, unsigned short* __restrict__ out,
                     const int* flags, int goff) {
  int bf = flags[0];
  int row = blockIdx.x * 4 + (threadIdx.x >> 6);
  int lane = threadIdx.x & 63;
  ushort8 u = *(const ushort8*)(x + (size_t)row * D + lane * 8);
  float v[8]; float s = 0.f, s2 = 0.f;
  for (int t = 0; t < 8; t++) {
    v[t] = b2f(u[t]); s += v[t]; s2 += v[t] * v[t];
  }
  for (int off = 32; off; off >>= 1) {
    s += __shfl_xor(s, off); s2 += __shfl_xor(s2, off);
  }
  float m = s / (float)D;
  float inv = rsqrtf(s2 / (float)D - m * m + 1e-5f);
  ushort8 ou;
  for (int t = 0; t < 8; t++) {
    int c = lane * 8 + t;
    ou[t] = f2b((v[t] - m) * inv * ldf(g, goff + c, bf) + ldf(bta, goff + c, bf));
  }
  *(ushort8*)(out + (size_t)row * D + lane * 8) = ou;
}

// ---------------------------------------------------------------------------
// k_lnloss: fused final LN + recon head (MFMA) + masked MSE.
// ---------------------------------------------------------------------------
__global__ __launch_bounds__(128) void k_lnloss(
    const unsigned short* __restrict__ tok, const float* __restrict__ lnw,
    const unsigned short* __restrict__ WpT, const float* __restrict__ patches,
    const float* __restrict__ stdev, const int* __restrict__ mask_i,
    float* scal) {
  constexpr int RS = 520;  // padded LDS row stride (elements)
  __shared__ __align__(16) unsigned short As[32 * RS];
  __shared__ __align__(16) unsigned short Bs[16 * RS];
  int bpI = blockIdx.x; int b = bpI >> 6, p = bpI & 63;
  int tid = threadIdx.x;
  int row = tid >> 2, cg = tid & 3;   // 4 threads per token row
  size_t tokbase = (size_t)(b * L + p * 32);
  float s = 0.f, s2 = 0.f;
  for (int i = 0; i < 16; i++) {
    int c = cg + i * 4;
    ushort8 u = *(const ushort8*)(tok + (tokbase + row) * D + c * 8);
    for (int t = 0; t < 8; t++) { float v = b2f(u[t]); s += v; s2 += v * v; }
  }
  s += __shfl_xor(s, 1); s += __shfl_xor(s, 2);
  s2 += __shfl_xor(s2, 1); s2 += __shfl_xor(s2, 2);
  float m = s / (float)D;
  float inv = rsqrtf(s2 / (float)D - m * m + 1e-5f);
  for (int i = 0; i < 16; i++) {
    int c = cg + i * 4;
    ushort8 u = *(const ushort8*)(tok + (tokbase + row) * D + c * 8);
    ushort8 o;
    for (int t = 0; t < 8; t++) {
      int col = c * 8 + t;
      o[t] = f2b((b2f(u[t]) - m) * inv * lnw[col] + lnw[512 + col]);
    }
    *(ushort8*)(As + row * RS + c * 8) = o;
  }
  for (int e = tid; e < 16 * 64; e += 128) {
    int r = e >> 6, c = e & 63;
    *(ushort8*)(Bs + r * RS + c * 8) = *(const ushort8*)(WpT + r * 512 + c * 8);
  }
  __syncthreads();
  int w = tid >> 6, lane = tid & 63, lane15 = lane & 15, q = lane >> 4;
  float4v acc = 0;
  for (int kt = 0; kt < 16; kt++) {
    short8 a = *(const short8*)(As + (w * 16 + lane15) * RS + kt * 32 + q * 8);
    short8 bfr = *(const short8*)(Bs + lane15 * RS + kt * 32 + q * 8);
    acc = __builtin_amdgcn_mfma_f32_16x16x32_bf16(a, bfr, acc, 0, 0, 0);
  }
  float local = 0.f;
  int t = lane15;
  for (int r = 0; r < 4; r++) {
    int v = w * 16 + q * 4 + r;
    int tokidx = b * 2048 + p * 32 + v;
    if (mask_i[tokidx]) {
      float recon = acc[r] + lnw[1024 + t];
      float diff = recon - patches[(size_t)tokidx * 16 + t];
      float sc = stdev[b * 32 + v];
      local += sc * sc * diff * diff;
    }
  }
  for (int off = 32; off; off >>= 1) local += __shfl_xor(local, off);
  if (lane == 0) atomicAdd(&scal[0], local);
}

__global__ void k_final(const float* scal, const int* flags, unsigned* out) {
  float denom = (float)flags[1] * (float)PL;
  if (denom == 0.f) denom = 1.f;
  float loss = scal[0] / denom;
  unsigned fb = __float_as_uint(loss);
  unsigned u = (fb + 0x7FFFu + ((fb >> 16) & 1u)) >> 16;
  out[0] = (u << 16) | u;
}

}  // namespace

extern "C" void kernel_launch(void* const* d_in, const int* in_sizes, int n_in,
                              void* d_out, int out_size, void* d_ws,
                              size_t ws_size, hipStream_t stream) {
  const void* x_enc = d_in[0];
  const void* maskp = d_in[1];
  const void* We = d_in[2];  const void* be_ = d_in[3];
  const void* Wq = d_in[4];  const void* bq = d_in[5];
  const void* Wk = d_in[6];  const void* bk = d_in[7];
  const void* Wv = d_in[8];  const void* bv = d_in[9];
  const void* Wo = d_in[10]; const void* bo_ = d_in[11];
  const void* W1 = d_in[12]; const void* b1 = d_in[13];
  const void* W2 = d_in[14]; const void* b2 = d_in[15];
  const void* g1 = d_in[16]; const void* be1 = d_in[17];
  const void* g2 = d_in[18]; const void* be2 = d_in[19];
  const void* gf = d_in[20]; const void* bff = d_in[21];
  const void* Wp = d_in[22]; const void* bp = d_in[23];

  constexpr size_t MB = 1u << 20;
  char* w = (char*)d_ws;
  int*   mask_i  = (int*)w;                        // 32 KB
  int*   flags   = (int*)(w + 32768);
  float* scal    = (float*)(w + 32896);
  float* means   = (float*)(w + 33024);
  float* stdev   = (float*)(w + 33600);
  float* biasf   = (float*)(w + 36864);            // 73728 B -> ends 110592
  float* lnw     = (float*)(w + 114688);           // 4160 B
  float* patches = (float*)(w + 131072);           // 512 KB -> ends 655360
  unsigned short* WpT = (unsigned short*)(w + 655360);    // 16 KB
  unsigned short* qkvT = (unsigned short*)(w + 1 * MB);   // 6 MB
  unsigned short* WoT  = (unsigned short*)(w + 7 * MB);   // 2 MB
  unsigned short* W1T  = (unsigned short*)(w + 9 * MB);   // 8 MB
  unsigned short* W2T  = (unsigned short*)(w + 17 * MB);  // 8 MB
  unsigned short* tok  = (unsigned short*)(w + 25 * MB);  // 8 MB
  unsigned short* tmp  = (unsigned short*)(w + 33 * MB);  // 8 MB
  unsigned short* ob   = (unsigned short*)(w + 41 * MB);  // 8 MB
  unsigned short* qk   = (unsigned short*)(w + 49 * MB);  // 16 MB -> ends 65
  unsigned short* vTb  = (unsigned short*)(w + 73 * MB);  // 8 MB -> ends 81
  unsigned short* hidden = ob;   // 32 MB alias over ob+qk (dead by FFN1)

  k_setup<<<1, 256, 0, stream>>>(gf, maskp, mask_i, flags, scal);
  k_prep<<<141, 256, 0, stream>>>(x_enc, bq, bk, bv, bo_, b1, b2, gf, bff, Wp,
                                  bp, flags, means, stdev, biasf, lnw, WpT);
  k_transpose_all<<<12288, 256, 0, stream>>>(Wq, Wk, Wv, Wo, W1, W2, qkvT, WoT,
                                             W1T, W2T, flags);
  k_embed<<<M, 128, 0, stream>>>(x_enc, We, be_, flags, mask_i, means, stdev,
                                 patches, tok);
  for (int l = 0; l < 4; l++) {
    k_gemm<128, 64, 32><<<1536, 256, 0, stream>>>(
        tok, qkvT + (size_t)l * 786432, biasf + l * 1536, nullptr, qk, vTb,
        1024, 512, 0, 24);
    k_attn<<<2048, 256, 0, stream>>>(qk, vTb, ob);
    k_gemm<64, 64, 16><<<1024, 256, 0, stream>>>(
        ob, WoT + (size_t)l * 262144, biasf + 6144 + l * 512, tok, tmp,
        nullptr, 512, 512, 0, 8);
    k_ln<<<M / 4, 256, 0, stream>>>(tmp, g1, be1, tok, flags, l * 512);
    k_gemm<128, 64, 32><<<2048, 256, 0, stream>>>(
        tok, W1T + (size_t)l * 1048576, biasf + 8192 + l * 2048, nullptr,
        hidden, nullptr, 2048, 512, 1, 32);
    k_gemm<64, 64, 16><<<1024, 256, 0, stream>>>(
        hidden, W2T + (size_t)l * 1048576, biasf + 16384 + l * 512, tok, tmp,
        nullptr, 512, 2048, 0, 8);
    k_ln<<<M / 4, 256, 0, stream>>>(tmp, g2, be2, tok, flags, l * 512);
  }
  k_lnloss<<<Bn * P, 128, 0, stream>>>(tok, lnw, WpT, patches, stdev, mask_i,
                                       scal);
  k_final<<<1, 1, 0, stream>>>(scal, flags, (unsigned*)d_out);
}

// Round 12
// 876.895 us; speedup vs baseline: 1.3889x; 1.0449x over previous
//
#include <hip/hip_runtime.h>
#include <hip/hip_bf16.h>

#define DEV __device__ __forceinline__

namespace {

constexpr int Bn  = 4, SEQ = 1024, NV = 32, PL = 16, D = 512, H = 8, DFF = 2048;
constexpr int P   = SEQ / PL;    // 64 patches
constexpr int L   = P * NV;      // 2048 tokens per batch
constexpr int M   = Bn * L;      // 8192 total token rows
constexpr int WIN = 4;

using short8   = __attribute__((ext_vector_type(8))) short;
using ushort8  = __attribute__((ext_vector_type(8))) unsigned short;
using float4v  = __attribute__((ext_vector_type(4))) float;

DEV float b2f(unsigned short u) { return __uint_as_float(((unsigned)u) << 16); }
DEV unsigned short f2b(float f) {   // RNE (used where bias matters)
  unsigned fb = __float_as_uint(f);
  return (unsigned short)((fb + 0x7FFFu + ((fb >> 16) & 1u)) >> 16);
}
DEV unsigned short f2bt(float f) {  // truncation: 1 VALU op
  return (unsigned short)(__float_as_uint(f) >> 16);
}
// flag-dispatched float load from an input tensor: bf=1 -> bf16, 0 -> fp32
DEV float ldf(const void* p, size_t idx, int bf) {
  if (bf) return b2f(((const unsigned short*)p)[idx]);
  return ((const float*)p)[idx];
}
// async global->LDS 16B: lds dest = wave-uniform base + lane*16
DEV void gll16(const void* gp, void* lp) {
  __builtin_amdgcn_global_load_lds(
      (const __attribute__((address_space(1))) void*)gp,
      (__attribute__((address_space(3))) void*)lp, 16, 0, 0);
}

// ---------------------------------------------------------------------------
// k_setup: detect float dtype + mask format, canonicalize mask, count masked.
// ---------------------------------------------------------------------------
__global__ void k_setup(const void* gf, const void* mask_raw, int* mask_i,
                        int* flags, float* scal) {
  __shared__ int s_gt1, s_oth, s_cnt;
  int tid = threadIdx.x;
  if (tid == 0) { s_gt1 = 0; s_oth = 0; s_cnt = 0; }
  __syncthreads();
  const unsigned* mw = (const unsigned*)mask_raw;
  int gt1 = 0, oth = 0;
  for (int i = tid; i < 2048; i += 256) {
    unsigned w = mw[i];
    if (w > 1u) { gt1 = 1; if (w != 0x3F800000u) oth = 1; }
  }
  if (gt1) atomicOr(&s_gt1, 1);
  if (oth) atomicOr(&s_oth, 1);
  __syncthreads();
  int fmt = (!s_gt1) ? 0 : (!s_oth ? 1 : 2);  // 0=int32, 1=f32, 2=bytes
  int cnt = 0;
  for (int i = tid; i < Bn * P * NV; i += 256) {
    int m;
    if (fmt == 0)      m = ((const int*)mask_raw)[i] != 0;
    else if (fmt == 1) m = ((const float*)mask_raw)[i] != 0.0f;
    else               m = ((const unsigned char*)mask_raw)[i] != 0;
    mask_i[i] = m; cnt += m;
  }
  atomicAdd(&s_cnt, cnt);
  __syncthreads();
  if (tid == 0) {
    unsigned w = *(const unsigned*)gf;
    flags[0] = ((w & 0xFFFFu) == 0x3F80u) ? 1 : 0;
    flags[1] = s_cnt;
    scal[0] = 0.f;
  }
}

// ---------------------------------------------------------------------------
// k_prep: blocks 0..31 -> per-(b,v) stats; blocks 32.. -> gather biases,
// final-LN weights (fp32), b_proj (fp32), and WpT (bf16 [t][d]).
// ---------------------------------------------------------------------------
__global__ void k_prep(const void* x, const void* bq, const void* bk,
                       const void* bv, const void* bo, const void* b1,
                       const void* b2, const void* gf, const void* bff,
                       const void* Wp, const void* bp, const int* flags,
                       float* means, float* stdev, float* biasf, float* lnw,
                       unsigned short* WpT) {
  int bf = flags[0];
  int tid = threadIdx.x;
  if (blockIdx.x < 32) {
    int bv_ = blockIdx.x * 4 + (tid >> 6);
    int b = bv_ >> 5, v = bv_ & 31;
    int lane = tid & 63;
    float s = 0.f, s2 = 0.f;
    for (int t = lane; t < SEQ; t += 64) {
      float val = ldf(x, (size_t)b * SEQ * NV + (size_t)t * NV + v, bf);
      s += val; s2 += val * val;
    }
    for (int off = 32; off; off >>= 1) {
      s += __shfl_xor(s, off); s2 += __shfl_xor(s2, off);
    }
    if (lane == 0) {
      float m = s / (float)SEQ;
      means[bv_] = m;
      stdev[bv_] = sqrtf(s2 / (float)SEQ - m * m + 1e-5f);
    }
    return;
  }
  int i = (blockIdx.x - 32) * 256 + tid;
  if (i < 18432) {
    int l = i / 4608, r = i % 4608;
    if (r < 1536) {
      float v = (r < 512) ? ldf(bq, l * 512 + r, bf)
              : (r < 1024) ? ldf(bk, l * 512 + r - 512, bf)
                           : ldf(bv, l * 512 + r - 1024, bf);
      biasf[l * 1536 + r] = v;
    } else if (r < 2048) {
      biasf[6144 + l * 512 + (r - 1536)] = ldf(bo, l * 512 + r - 1536, bf);
    } else if (r < 4096) {
      biasf[8192 + l * 2048 + (r - 2048)] = ldf(b1, l * 2048 + r - 2048, bf);
    } else {
      biasf[16384 + l * 512 + (r - 4096)] = ldf(b2, l * 512 + r - 4096, bf);
    }
  } else if (i < 19456) {
    int j = i - 18432;
    lnw[j] = (j < 512) ? ldf(gf, j, bf) : ldf(bff, j - 512, bf);
  } else if (i < 19472) {
    lnw[1024 + (i - 19456)] = ldf(bp, i - 19456, bf);
  } else if (i < 27664) {
    int j = i - 19472; int t = j >> 9, d = j & 511;
    WpT[j] = f2b(ldf(Wp, d * 16 + t, bf));
  }
}

// ---------------------------------------------------------------------------
// k_transpose_all: all 6 weight transposes in one dispatch.
// dst[l][n][k] (bf16) = src[l][k][n]. 32x32 LDS tile per block.
// ---------------------------------------------------------------------------
__global__ void k_transpose_all(const void* Wq, const void* Wk, const void* Wv,
                                const void* Wo, const void* W1, const void* W2,
                                unsigned short* qkvT, unsigned short* WoT,
                                unsigned short* W1T, unsigned short* W2T,
                                const int* flags) {
  int bf = flags[0];
  int id = blockIdx.x;
  const void* src; unsigned short* dst;
  int Kd, Nd, l, n0, k0, dstOff = 0;
  size_t srcLS, dstLS;
  if (id < 4096) {
    int tensor = id >> 10, rem = id & 1023;
    l = rem >> 8; int t = rem & 255;
    n0 = (t & 15) * 32; k0 = (t >> 4) * 32;
    Kd = 512; Nd = 512; srcLS = 262144;
    if (tensor == 0)      { src = Wq; dst = qkvT; dstLS = 786432; dstOff = 0; }
    else if (tensor == 1) { src = Wk; dst = qkvT; dstLS = 786432; dstOff = 262144; }
    else if (tensor == 2) { src = Wv; dst = qkvT; dstLS = 786432; dstOff = 524288; }
    else                  { src = Wo; dst = WoT;  dstLS = 262144; }
  } else if (id < 8192) {
    int rem = id - 4096; l = rem >> 10; int t = rem & 1023;
    n0 = (t & 63) * 32; k0 = (t >> 6) * 32;
    Kd = 512; Nd = 2048; srcLS = 1048576; src = W1; dst = W1T; dstLS = 1048576;
  } else {
    int rem = id - 8192; l = rem >> 10; int t = rem & 1023;
    n0 = (t & 15) * 32; k0 = (t >> 4) * 32;
    Kd = 2048; Nd = 512; srcLS = 1048576; src = W2; dst = W2T; dstLS = 1048576;
  }
  int tx = threadIdx.x & 31, ty = threadIdx.x >> 5;
  __shared__ float tile[32][33];
  for (int rr = ty; rr < 32; rr += 8)
    tile[rr][tx] =
        ldf(src, (size_t)l * srcLS + (size_t)(k0 + rr) * Nd + n0 + tx, bf);
  __syncthreads();
  for (int rr = ty; rr < 32; rr += 8)
    dst[(size_t)l * dstLS + dstOff + (size_t)(n0 + rr) * Kd + k0 + tx] =
        f2b(tile[tx][rr]);
}

// ---------------------------------------------------------------------------
// k_embed: patchify + instance-normalize, write patches (fp32) and embedded
// tokens (bf16), zeroing masked tokens. One block (128 thr) per token.
// ---------------------------------------------------------------------------
__global__ void k_embed(const void* x, const void* We, const void* be,
                        const int* flags, const int* mask_i,
                        const float* means, const float* stdev,
                        float* patches, unsigned short* tok) {
  int idx = blockIdx.x;
  int b = idx >> 11, pv = idx & 2047, p = pv >> 5, v = pv & 31;
  int bf = flags[0];
  __shared__ float pvs[PL];
  int tid = threadIdx.x;
  float m = means[b * NV + v], sd = stdev[b * NV + v];
  if (tid < PL) {
    float val =
        (ldf(x, (size_t)b * SEQ * NV + (size_t)(p * PL + tid) * NV + v, bf) -
         m) / sd;
    pvs[tid] = val;
    patches[(size_t)idx * PL + tid] = val;
  }
  __syncthreads();
  int masked = mask_i[idx];
  for (int d = tid; d < D; d += 128) {
    float acc = ldf(be, d, bf);
    for (int t = 0; t < PL; t++) acc += pvs[t] * ldf(We, t * D + d, bf);
    tok[(size_t)idx * D + d] = masked ? f2b(0.f) : f2b(acc);
  }
}

// ---------------------------------------------------------------------------
// k_gemm<BM,BN,WN>: C = act(A @ W^T' + bias [+resid]) in bf16. BK=64.
// Linear grid, XCD-swizzled. Epilogue through LDS for coalesced ushort8 IO.
// vTp != null (QKV): bn >= 1024 tiles are V (staged transposed -> vT); q
// tiles (bn < 512) are pre-scaled by SCALE=0.125 so attention needs no scale.
// ---------------------------------------------------------------------------
template <int BM, int BN, int WN>
__global__ __launch_bounds__(256) void k_gemm(
    const unsigned short* __restrict__ A, const unsigned short* __restrict__ W,
    const float* __restrict__ bias, const unsigned short* __restrict__ resid,
    unsigned short* __restrict__ C, unsigned short* __restrict__ vTp, int cs,
    int Kk, int act, int nbn) {
  constexpr int FI = 4, FJ = WN / 16, NWN = BN / WN;
  __shared__ __align__(16) char sm[BM * 128 + BN * 128];
  char* As = sm;
  char* Bs = sm + BM * 128;
  unsigned short* Cl = (unsigned short*)sm;
  int tid = threadIdx.x, lane = tid & 63, w = tid >> 6;
  int lane15 = lane & 15, q = lane >> 4;
  int wm = w / NWN, wn = w % NWN;
  int id = blockIdx.x;
  int xcd = id & 7, loc = id >> 3;
  int bn = (loc % nbn) * BN;
  int bm = (xcd * ((int)(gridDim.x >> 3) / nbn) + loc / nbn) * BM;
  int lrow = lane >> 3, lc = lane & 7;
  float4v acc[FI][FJ];
  for (int i = 0; i < FI; i++)
    for (int j = 0; j < FJ; j++) acc[i][j] = 0;
  for (int k0 = 0; k0 < Kk; k0 += 64) {
    if (k0) __syncthreads();
    for (int i = w; i < BM / 8; i += 4) {
      int row = i * 8 + lrow;
      gll16(A + (size_t)(bm + row) * Kk + k0 + ((lc ^ (row & 7)) << 3),
            As + i * 1024);
    }
    for (int i = w; i < BN / 8; i += 4) {
      int row = i * 8 + lrow;
      gll16(W + (size_t)(bn + row) * Kk + k0 + ((lc ^ (row & 7)) << 3),
            Bs + i * 1024);
    }
    __syncthreads();
    short8 a[2][FI], b[2][FJ];
    for (int h = 0; h < 2; h++) {
      for (int i = 0; i < FI; i++) {
        int rr = wm * 64 + i * 16 + lane15;
        a[h][i] =
            *(const short8*)(As + rr * 128 + (((h * 4 + q) ^ (rr & 7)) << 4));
      }
      for (int j = 0; j < FJ; j++) {
        int rr = wn * WN + j * 16 + lane15;
        b[h][j] =
            *(const short8*)(Bs + rr * 128 + (((h * 4 + q) ^ (rr & 7)) << 4));
      }
    }
    for (int h = 0; h < 2; h++)
      for (int i = 0; i < FI; i++)
        for (int j = 0; j < FJ; j++)
          acc[i][j] = __builtin_amdgcn_mfma_f32_16x16x32_bf16(
              a[h][i], b[h][j], acc[i][j], 0, 0, 0);
  }
  // ---- epilogue through LDS ----
  int vmode = (vTp != nullptr) && (bn >= 1024);
  float oscale = (vTp != nullptr && bn < 512) ? 0.125f : 1.0f;  // q pre-scale
  __syncthreads();  // all MFMAs done reading As/Bs
  for (int i = 0; i < FI; i++) {
    for (int j = 0; j < FJ; j++) {
      int col = wn * WN + j * 16 + lane15;        // tile-local col
      float bv = bias[bn + col];
      for (int r = 0; r < 4; r++) {
        int row = wm * 64 + i * 16 + q * 4 + r;   // tile-local row
        float cv = (acc[i][j][r] + bv) * oscale;
        if (act) {  // fast GELU: x * sigmoid(1.5958x + 0.07135x^3)
          float t = cv * (1.5957692f + 0.0713548f * cv * cv);
          cv = cv / (1.f + __expf(-t));
        }
        if (!vmode)
          Cl[row * BN + (((col >> 3) ^ (row & 7)) << 3) + (col & 7)] = f2bt(cv);
        else
          Cl[col * BM + (((row >> 3) ^ (col & 7)) << 3) + (row & 7)] = f2bt(cv);
      }
    }
  }
  __syncthreads();
  if (!vmode) {
    constexpr int TOT = BM * BN / 8;
    for (int e = tid; e < TOT; e += 256) {
      int rr = e / (BN / 8), c8 = e % (BN / 8);
      ushort8 u = *(const ushort8*)(Cl + rr * BN + ((c8 ^ (rr & 7)) << 3));
      size_t off = (size_t)(bm + rr) * cs + bn + c8 * 8;
      if (resid) {
        ushort8 rv = *(const ushort8*)(resid + off);
        for (int t = 0; t < 8; t++) u[t] = f2bt(b2f(u[t]) + b2f(rv[t]));
      }
      *(ushort8*)(C + off) = u;
    }
  } else {
    constexpr int TOT = BM * BN / 8;
    for (int e = tid; e < TOT; e += 256) {
      int cc = e / (BM / 8), t8 = e % (BM / 8);
      ushort8 u = *(const ushort8*)(Cl + cc * BM + ((t8 ^ (cc & 7)) << 3));
      int hd = bn - 1024 + cc;
      int rowg = bm + t8 * 8;
      int bb = rowg >> 11, tokin = rowg & 2047;
      *(ushort8*)(vTp + ((size_t)(bb * 512 + hd)) * 2048 + tokin) = u;
    }
  }
}

// ---------------------------------------------------------------------------
// k_attn: banded MFMA attention, fragment-direct global loads. R12: each
// wave owns a DISTINCT quarter of the n-tiles and computes BOTH m-tiles
// (R11's pairing had wave pairs loading identical K/V fragments — 2x the
// vmem requests in a request-latency-bound kernel). 19.5 KB LDS, VGPR <64
// -> 8 blocks/CU (R7: LDS K-staging at 56 KB halved speed; keep <=20KB).
// q pre-scaled by 0.125 in QKV GEMM; softmax skips max-sub (|s| <~ 5).
// ---------------------------------------------------------------------------
__global__ __launch_bounds__(256) void k_attn(
    const unsigned short* __restrict__ qk,
    const unsigned short* __restrict__ vT, unsigned short* __restrict__ o) {
  constexpr int SSTR = 304;
  __shared__ __align__(16) unsigned short S[32 * SSTR];
  int id = blockIdx.x;
  int xcd = id & 7, rr_ = id >> 3;
  int p = xcd * 8 + (rr_ & 7);
  int h = (rr_ >> 3) & 7;
  int b = rr_ >> 6;
  int tid = threadIdx.x, lane = tid & 63, w = tid >> 6;
  int lane15 = lane & 15, q = lane >> 4;
  int p0 = max(0, p - WIN), p1 = min(P - 1, p + WIN);
  int nk = (p1 - p0 + 1) * 32;     // multiple of 32, in [160,288]
  int ntiles = nk >> 4;
  size_t base = (size_t)b * L;
  // Q fragments for BOTH m-tiles (A-operand), direct global
  short8 aq[2][2];
  for (int m = 0; m < 2; m++) {
    const unsigned short* qrow =
        qk + (base + p * 32 + m * 16 + lane15) * 1024 + h * 64 + q * 8;
    aq[m][0] = *(const short8*)(qrow);
    aq[m][1] = *(const short8*)(qrow + 32);
  }
  const unsigned short* kbase =
      qk + (base + p0 * 32) * 1024 + 512 + h * 64 + q * 8;
  // phase A: wave w handles nt = w, w+4, ... (no duplicate K loads)
  {
    int nt = w;
    const unsigned short* kr = kbase + (size_t)(nt * 16 + lane15) * 1024;
    short8 c0, c1, n0, n1;
    if (nt < ntiles) {
      c0 = *(const short8*)(kr);
      c1 = *(const short8*)(kr + 32);
    }
    if (nt + 4 < ntiles) {
      kr = kbase + (size_t)((nt + 4) * 16 + lane15) * 1024;
      n0 = *(const short8*)(kr);
      n1 = *(const short8*)(kr + 32);
    }
    for (; nt < ntiles; nt += 4) {
      short8 m0, m1;
      if (nt + 8 < ntiles) {
        kr = kbase + (size_t)((nt + 8) * 16 + lane15) * 1024;
        m0 = *(const short8*)(kr);
        m1 = *(const short8*)(kr + 32);
      }
      for (int m = 0; m < 2; m++) {
        float4v s4 = 0;
        s4 = __builtin_amdgcn_mfma_f32_16x16x32_bf16(aq[m][0], c0, s4, 0, 0, 0);
        s4 = __builtin_amdgcn_mfma_f32_16x16x32_bf16(aq[m][1], c1, s4, 0, 0, 0);
        for (int r = 0; r < 4; r++)
          S[(m * 16 + q * 4 + r) * SSTR + nt * 16 + lane15] = f2b(s4[r]);
      }
      c0 = n0; c1 = n1; n0 = m0; n1 = m1;
    }
  }
  __syncthreads();
  // phase B: softmax without max-sub, b128 LDS IO, trunc P pack
  {
    int row = tid >> 3, c = tid & 7;
    ushort8 eb[5];
    float sum = 0.f;
    for (int k = 0; k < 5; k++) {
      int j0 = c * 8 + k * 64;
      if (j0 < nk) {
        ushort8 u = *(const ushort8*)(S + row * SSTR + j0);
        ushort8 e8;
        for (int t = 0; t < 8; t++) {
          float e = __expf(b2f(u[t]));
          sum += e;
          e8[t] = f2bt(e);
        }
        eb[k] = e8;
      }
    }
    for (int off = 1; off < 8; off <<= 1) sum += __shfl_xor(sum, off);
    float inv = 1.f / sum;
    for (int k = 0; k < 5; k++) {
      int j0 = c * 8 + k * 64;
      if (j0 < nk) {
        ushort8 e8 = eb[k], u;
        for (int t = 0; t < 8; t++) u[t] = f2bt(b2f(e8[t]) * inv);
        *(ushort8*)(S + row * SSTR + j0) = u;
      }
    }
  }
  __syncthreads();
  // phase C: O = P V. Wave w owns column tile w (16 cols), both m-tiles --
  // one V load per kt feeds 2 MFMAs (no duplicate V loads across waves).
  int nkt = nk >> 5;
  const unsigned short* vb =
      vT + (size_t)(b * 512 + h * 64 + w * 16 + lane15) * 2048 + p0 * 32 +
      q * 8;
  const unsigned short* pr0 = S + lane15 * SSTR + q * 8;
  const unsigned short* pr1 = S + (16 + lane15) * SSTR + q * 8;
  float4v oa0 = 0, oa1 = 0;
  short8 ap0 = *(const short8*)(pr0);
  short8 ap1 = *(const short8*)(pr1);
  short8 v0 = *(const short8*)(vb);
  for (int kt = 0; kt < nkt; kt++) {
    short8 a0N, a1N, v0N;
    if (kt + 1 < nkt) {
      a0N = *(const short8*)(pr0 + (kt + 1) * 32);
      a1N = *(const short8*)(pr1 + (kt + 1) * 32);
      v0N = *(const short8*)(vb + (kt + 1) * 32);
    }
    oa0 = __builtin_amdgcn_mfma_f32_16x16x32_bf16(ap0, v0, oa0, 0, 0, 0);
    oa1 = __builtin_amdgcn_mfma_f32_16x16x32_bf16(ap1, v0, oa1, 0, 0, 0);
    ap0 = a0N; ap1 = a1N; v0 = v0N;
  }
  // stage O in LDS (reuse S), then store full 128B lines cooperatively
  __syncthreads();
  for (int r = 0; r < 4; r++) {
    S[(q * 4 + r) * 72 + w * 16 + lane15] = f2bt(oa0[r]);
    S[(16 + q * 4 + r) * 72 + w * 16 + lane15] = f2bt(oa1[r]);
  }
  __syncthreads();
  {
    int row = tid >> 3, c8 = tid & 7;
    ushort8 val = *(const ushort8*)(S + row * 72 + c8 * 8);
    *(ushort8*)(o + (base + p * 32 + row) * 512 + h * 64 + c8 * 8) = val;
  }
}

// ---------------------------------------------------------------------------
// k_ln: layernorm over D=512 per token, bf16 in/out. 4 rows per block.
// ---------------------------------------------------------------------------
__global__ void k_ln(const unsigned short* __restrict__ x, const void* g,
                     const void* bta, unsigned short* __restrict__ out,
                     const int* flags, int goff) {
  int bf = flags[0];
  int row = blockIdx.x * 4 + (threadIdx.x >> 6);
  int lane = threadIdx.x & 63;
  ushort8 u = *(const ushort8*)(x + (size_t)row * D + lane * 8);
  float v[8]; float s = 0.f, s2 = 0.f;
  for (int t = 0; t < 8; t++) {
    v[t] = b2f(u[t]); s += v[t]; s2 += v[t] * v[t];
  }
  for (int off = 32; off; off >>= 1) {
    s += __shfl_xor(s, off); s2 += __shfl_xor(s2, off);
  }
  float m = s / (float)D;
  float inv = rsqrtf(s2 / (float)D - m * m + 1e-5f);
  ushort8 ou;
  for (int t = 0; t < 8; t++) {
    int c = lane * 8 + t;
    ou[t] = f2b((v[t] - m) * inv * ldf(g, goff + c, bf) + ldf(bta, goff + c, bf));
  }
  *(ushort8*)(out + (size_t)row * D + lane * 8) = ou;
}

// ---------------------------------------------------------------------------
// k_lnloss: fused final LN + recon head (MFMA) + masked MSE.
// ---------------------------------------------------------------------------
__global__ __launch_bounds__(128) void k_lnloss(
    const unsigned short* __restrict__ tok, const float* __restrict__ lnw,
    const unsigned short* __restrict__ WpT, const float* __restrict__ patches,
    const float* __restrict__ stdev, const int* __restrict__ mask_i,
    float* scal) {
  constexpr int RS = 520;  // padded LDS row stride (elements)
  __shared__ __align__(16) unsigned short As[32 * RS];
  __shared__ __align__(16) unsigned short Bs[16 * RS];
  int bpI = blockIdx.x; int b = bpI >> 6, p = bpI & 63;
  int tid = threadIdx.x;
  int row = tid >> 2, cg = tid & 3;   // 4 threads per token row
  size_t tokbase = (size_t)(b * L + p * 32);
  float s = 0.f, s2 = 0.f;
  for (int i = 0; i < 16; i++) {
    int c = cg + i * 4;
    ushort8 u = *(const ushort8*)(tok + (tokbase + row) * D + c * 8);
    for (int t = 0; t < 8; t++) { float v = b2f(u[t]); s += v; s2 += v * v; }
  }
  s += __shfl_xor(s, 1); s += __shfl_xor(s, 2);
  s2 += __shfl_xor(s2, 1); s2 += __shfl_xor(s2, 2);
  float m = s / (float)D;
  float inv = rsqrtf(s2 / (float)D - m * m + 1e-5f);
  for (int i = 0; i < 16; i++) {
    int c = cg + i * 4;
    ushort8 u = *(const ushort8*)(tok + (tokbase + row) * D + c * 8);
    ushort8 o;
    for (int t = 0; t < 8; t++) {
      int col = c * 8 + t;
      o[t] = f2b((b2f(u[t]) - m) * inv * lnw[col] + lnw[512 + col]);
    }
    *(ushort8*)(As + row * RS + c * 8) = o;
  }
  for (int e = tid; e < 16 * 64; e += 128) {
    int r = e >> 6, c = e & 63;
    *(ushort8*)(Bs + r * RS + c * 8) = *(const ushort8*)(WpT + r * 512 + c * 8);
  }
  __syncthreads();
  int w = tid >> 6, lane = tid & 63, lane15 = lane & 15, q = lane >> 4;
  float4v acc = 0;
  for (int kt = 0; kt < 16; kt++) {
    short8 a = *(const short8*)(As + (w * 16 + lane15) * RS + kt * 32 + q * 8);
    short8 bfr = *(const short8*)(Bs + lane15 * RS + kt * 32 + q * 8);
    acc = __builtin_amdgcn_mfma_f32_16x16x32_bf16(a, bfr, acc, 0, 0, 0);
  }
  float local = 0.f;
  int t = lane15;
  for (int r = 0; r < 4; r++) {
    int v = w * 16 + q * 4 + r;
    int tokidx = b * 2048 + p * 32 + v;
    if (mask_i[tokidx]) {
      float recon = acc[r] + lnw[1024 + t];
      float diff = recon - patches[(size_t)tokidx * 16 + t];
      float sc = stdev[b * 32 + v];
      local += sc * sc * diff * diff;
    }
  }
  for (int off = 32; off; off >>= 1) local += __shfl_xor(local, off);
  if (lane == 0) atomicAdd(&scal[0], local);
}

__global__ void k_final(const float* scal, const int* flags, unsigned* out) {
  float denom = (float)flags[1] * (float)PL;
  if (denom == 0.f) denom = 1.f;
  float loss = scal[0] / denom;
  unsigned fb = __float_as_uint(loss);
  unsigned u = (fb + 0x7FFFu + ((fb >> 16) & 1u)) >> 16;
  out[0] = (u << 16) | u;
}

}  // namespace

extern "C" void kernel_launch(void* const* d_in, const int* in_sizes, int n_in,
                              void* d_out, int out_size, void* d_ws,
                              size_t ws_size, hipStream_t stream) {
  const void* x_enc = d_in[0];
  const void* maskp = d_in[1];
  const void* We = d_in[2];  const void* be_ = d_in[3];
  const void* Wq = d_in[4];  const void* bq = d_in[5];
  const void* Wk = d_in[6];  const void* bk = d_in[7];
  const void* Wv = d_in[8];  const void* bv = d_in[9];
  const void* Wo = d_in[10]; const void* bo_ = d_in[11];
  const void* W1 = d_in[12]; const void* b1 = d_in[13];
  const void* W2 = d_in[14]; const void* b2 = d_in[15];
  const void* g1 = d_in[16]; const void* be1 = d_in[17];
  const void* g2 = d_in[18]; const void* be2 = d_in[19];
  const void* gf = d_in[20]; const void* bff = d_in[21];
  const void* Wp = d_in[22]; const void* bp = d_in[23];

  constexpr size_t MB = 1u << 20;
  char* w = (char*)d_ws;
  int*   mask_i  = (int*)w;                        // 32 KB
  int*   flags   = (int*)(w + 32768);
  float* scal    = (float*)(w + 32896);
  float* means   = (float*)(w + 33024);
  float* stdev   = (float*)(w + 33600);
  float* biasf   = (float*)(w + 36864);            // 73728 B -> ends 110592
  float* lnw     = (float*)(w + 114688);           // 4160 B
  float* patches = (float*)(w + 131072);           // 512 KB -> ends 655360
  unsigned short* WpT = (unsigned short*)(w + 655360);    // 16 KB
  unsigned short* qkvT = (unsigned short*)(w + 1 * MB);   // 6 MB
  unsigned short* WoT  = (unsigned short*)(w + 7 * MB);   // 2 MB
  unsigned short* W1T  = (unsigned short*)(w + 9 * MB);   // 8 MB
  unsigned short* W2T  = (unsigned short*)(w + 17 * MB);  // 8 MB
  unsigned short* tok  = (unsigned short*)(w + 25 * MB);  // 8 MB
  unsigned short* tmp  = (unsigned short*)(w + 33 * MB);  // 8 MB
  unsigned short* ob   = (unsigned short*)(w + 41 * MB);  // 8 MB
  unsigned short* qk   = (unsigned short*)(w + 49 * MB);  // 16 MB -> ends 65
  unsigned short* vTb  = (unsigned short*)(w + 73 * MB);  // 8 MB -> ends 81
  unsigned short* hidden = ob;   // 32 MB alias over ob+qk (dead by FFN1)

  k_setup<<<1, 256, 0, stream>>>(gf, maskp, mask_i, flags, scal);
  k_prep<<<141, 256, 0, stream>>>(x_enc, bq, bk, bv, bo_, b1, b2, gf, bff, Wp,
                                  bp, flags, means, stdev, biasf, lnw, WpT);
  k_transpose_all<<<12288, 256, 0, stream>>>(Wq, Wk, Wv, Wo, W1, W2, qkvT, WoT,
                                             W1T, W2T, flags);
  k_embed<<<M, 128, 0, stream>>>(x_enc, We, be_, flags, mask_i, means, stdev,
                                 patches, tok);
  for (int l = 0; l < 4; l++) {
    k_gemm<128, 64, 32><<<1536, 256, 0, stream>>>(
        tok, qkvT + (size_t)l * 786432, biasf + l * 1536, nullptr, qk, vTb,
        1024, 512, 0, 24);
    k_attn<<<2048, 256, 0, stream>>>(qk, vTb, ob);
    k_gemm<64, 64, 16><<<1024, 256, 0, stream>>>(
        ob, WoT + (size_t)l * 262144, biasf + 6144 + l * 512, tok, tmp,
        nullptr, 512, 512, 0, 8);
    k_ln<<<M / 4, 256, 0, stream>>>(tmp, g1, be1, tok, flags, l * 512);
    k_gemm<128, 64, 32><<<2048, 256, 0, stream>>>(
        tok, W1T + (size_t)l * 1048576, biasf + 8192 + l * 2048, nullptr,
        hidden, nullptr, 2048, 512, 1, 32);
    k_gemm<64, 64, 16><<<1024, 256, 0, stream>>>(
        hidden, W2T + (size_t)l * 1048576, biasf + 16384 + l * 512, tok, tmp,
        nullptr, 512, 2048, 0, 8);
    k_ln<<<M / 4, 256, 0, stream>>>(tmp, g2, be2, tok, flags, l * 512);
  }
  k_lnloss<<<Bn * P, 128, 0, stream>>>(tok, lnw, WpT, patches, stdev, mask_i,
                                       scal);
  k_final<<<1, 1, 0, stream>>>(scal, flags, (unsigned*)d_out);
}